// Round 1
// baseline (988.819 us; speedup 1.0000x reference)
//
#include <hip/hip_runtime.h>

#define N_ENT   100000
#define N_USR   4096
#define N_ITEM  8192
#define N_REL   32
#define N_CLS   3
#define DD      128
#define N_EDGES 800000
#define NNZ     204800

typedef __attribute__((ext_vector_type(8))) short short8;
typedef __attribute__((ext_vector_type(4))) float f32x4;

// manual f32 -> bf16 round-to-nearest-even (inputs finite)
static __device__ __forceinline__ unsigned short f2bf(float x) {
    unsigned int u = __builtin_bit_cast(unsigned int, x);
    u = (u + 0x7fffu + ((u >> 16) & 1u)) >> 16;
    return (unsigned short)u;
}

// ---------------- K1: ent_rel_att = softmax(entity_emb @ relation_emb^T) ----
__global__ __launch_bounds__(256) void k_ent_att(const float* __restrict__ ent,
                                                 const float* __restrict__ rel,
                                                 float* __restrict__ att) {
    __shared__ float srel[N_REL * DD];
    for (int i = threadIdx.x; i < N_REL * DD; i += 256) srel[i] = rel[i];
    __syncthreads();
    int e = blockIdx.x * 256 + threadIdx.x;
    if (e >= N_ENT) return;
    const float4* row = (const float4*)(ent + (size_t)e * DD);
    float acc[N_REL];
#pragma unroll
    for (int r = 0; r < N_REL; ++r) acc[r] = 0.f;
    for (int dq = 0; dq < DD / 4; ++dq) {
        float4 v = row[dq];
#pragma unroll
        for (int r = 0; r < N_REL; ++r) {
            float4 w = *(const float4*)&srel[r * DD + dq * 4];
            acc[r] += v.x * w.x + v.y * w.y + v.z * w.z + v.w * w.w;
        }
    }
    float m = acc[0];
#pragma unroll
    for (int r = 1; r < N_REL; ++r) m = fmaxf(m, acc[r]);
    float s = 0.f;
#pragma unroll
    for (int r = 0; r < N_REL; ++r) { acc[r] = __expf(acc[r] - m); s += acc[r]; }
    float inv = 1.f / s;
    float* o = att + (size_t)e * N_REL;
#pragma unroll
    for (int r = 0; r < N_REL; ++r) o[r] = acc[r] * inv;
}

// ---------------- K2: edge aggregation (wave per edge, f32 atomics) --------
__global__ __launch_bounds__(256) void k_edge_agg(const float* __restrict__ ent,
                                                  const float* __restrict__ rel,
                                                  const int* __restrict__ eidx,
                                                  const int* __restrict__ etyp,
                                                  const float* __restrict__ eimp,
                                                  const float* __restrict__ att,
                                                  float* __restrict__ out) {
    int lane = threadIdx.x & 63;
    int e = __builtin_amdgcn_readfirstlane(blockIdx.x * 4 + (threadIdx.x >> 6));
    int h  = eidx[e];
    int tl = eidx[N_EDGES + e];
    int r  = etyp[e];
    float s = att[(size_t)h * N_REL + r] * eimp[e];
    float2 a = ((const float2*)(rel + (size_t)r  * DD))[lane];
    float2 b = ((const float2*)(ent + (size_t)tl * DD))[lane];
    float* dst = out + (size_t)h * DD + lane * 2;
    unsafeAtomicAdd(dst,     a.x * b.x * s);
    unsafeAtomicAdd(dst + 1, a.y * b.y * s);
}

// ---------------- K3: user sparse gather (wave per nnz) --------------------
__global__ __launch_bounds__(256) void k_user_gather(const float* __restrict__ ent,
                                                     const int* __restrict__ rows,
                                                     const int* __restrict__ cols,
                                                     const float* __restrict__ vals,
                                                     float* __restrict__ uout) {
    int lane = threadIdx.x & 63;
    int e = __builtin_amdgcn_readfirstlane(blockIdx.x * 4 + (threadIdx.x >> 6));
    int u = rows[e];
    int c = cols[e];
    float v = vals[e];
    float2 b = ((const float2*)(ent + (size_t)c * DD))[lane];
    float* dst = uout + (size_t)u * DD + lane * 2;
    unsafeAtomicAdd(dst,     b.x * v);
    unsafeAtomicAdd(dst + 1, b.y * v);
}

// ---------------- K4b: Bt[d][i] = bf16(item[i][d] * sum_r rel[r][d]) -------
__global__ __launch_bounds__(256) void k_item2(const float* __restrict__ item,
                                               const float* __restrict__ rel,
                                               unsigned short* __restrict__ Bt) {
    int d = blockIdx.y;                       // uniform -> scalar loads of rel
    int i = blockIdx.x * 256 + threadIdx.x;
    float s = 0.f;
    for (int r = 0; r < N_REL; ++r) s += rel[r * DD + d];
    float v = item[(size_t)i * DD + d] * s;
    Bt[(size_t)d * N_ITEM + i] = f2bf(v);
}

// ---------------- K4c: user_cls_att = softmax(user_emb @ usr_cls_w^T) ------
__global__ __launch_bounds__(256) void k_user_att(const float* __restrict__ usr,
                                                  const float* __restrict__ w,
                                                  float* __restrict__ att) {
    __shared__ float sw[N_CLS * DD];
    for (int i = threadIdx.x; i < N_CLS * DD; i += 256) sw[i] = w[i];
    __syncthreads();
    int u = blockIdx.x * 256 + threadIdx.x;
    const float4* row = (const float4*)(usr + (size_t)u * DD);
    float acc[3] = {0.f, 0.f, 0.f};
    for (int dq = 0; dq < DD / 4; ++dq) {
        float4 v = row[dq];
#pragma unroll
        for (int c = 0; c < 3; ++c) {
            float4 ww = *(const float4*)&sw[c * DD + dq * 4];
            acc[c] += v.x * ww.x + v.y * ww.y + v.z * ww.z + v.w * ww.w;
        }
    }
    float m = fmaxf(acc[0], fmaxf(acc[1], acc[2]));
    float s = 0.f;
#pragma unroll
    for (int c = 0; c < 3; ++c) { acc[c] = __expf(acc[c] - m); s += acc[c]; }
    float inv = 1.f / s;
#pragma unroll
    for (int c = 0; c < 3; ++c) att[u * 3 + c] = acc[c] * inv;
}

// ---------------- K5: fused disen GEMM ------------------------------------
// user_agg[u,d] += sum_i (sum_c att[u,c]*icm[c,u,i]) * item2[i,d]
// M=4096, K=8192, N=128. bf16 MFMA 16x16x32, BM=64, BK=32, SPLIT_K=16.
#define BM 64
#define BK 32
#define SPLITK 16
#define KCH (N_ITEM / SPLITK)                 // 512
#define PLANE ((long long)N_USR * N_ITEM)     // 33,554,432 elems

__global__ __launch_bounds__(256) void k_disen_gemm(const float* __restrict__ icm,
                                                    const unsigned short* __restrict__ Bt,
                                                    const float* __restrict__ uatt,
                                                    float* __restrict__ uout) {
    __shared__ unsigned short sA[BM][40];     // [u][k] bf16, pad 32->40 (2-way only)
    __shared__ unsigned short sB[DD][40];     // [d][k] bf16

    const int t  = threadIdx.x;
    const int m0 = blockIdx.x * BM;
    const long long k0b = (long long)blockIdx.y * KCH;

    // A staging map: flat float4 index f in [0,512): u=f>>3, q=f&7; f = t and t+256
    const int ua = t >> 3;                    // 0..31
    const int qa = t & 7;
    const float a00 = uatt[(m0 + ua) * 3 + 0];
    const float a01 = uatt[(m0 + ua) * 3 + 1];
    const float a02 = uatt[(m0 + ua) * 3 + 2];
    const float a10 = uatt[(m0 + ua + 32) * 3 + 0];
    const float a11 = uatt[(m0 + ua + 32) * 3 + 1];
    const float a12 = uatt[(m0 + ua + 32) * 3 + 2];

    // B staging map: flat 16B-chunk index f in [0,512): d=f>>2, q=f&3
    const int db = t >> 2;                    // 0..63
    const int qb = t & 3;

    const int lane = t & 63;
    const int wv = t >> 6;
    const int wm = wv >> 1, wn = wv & 1;      // 2x2 waves -> 32u x 64d each
    const int la = lane & 15, lb = lane >> 4;

    f32x4 acc[2][4];
#pragma unroll
    for (int mi = 0; mi < 2; ++mi)
#pragma unroll
        for (int ni = 0; ni < 4; ++ni) {
            f32x4 z = {0.f, 0.f, 0.f, 0.f};
            acc[mi][ni] = z;
        }

    for (int kk = 0; kk < KCH; kk += BK) {
        const long long k0 = k0b + kk;
        // ---- stage A: combine 3 planes with att weights, convert to bf16 ----
        {
            const long long base0 = (long long)(m0 + ua) * N_ITEM + k0 + qa * 4;
            float4 v0 = *(const float4*)(icm + base0);
            float4 v1 = *(const float4*)(icm + base0 + PLANE);
            float4 v2 = *(const float4*)(icm + base0 + 2 * PLANE);
            ushort4 p;
            p.x = f2bf(a00 * v0.x + a01 * v1.x + a02 * v2.x);
            p.y = f2bf(a00 * v0.y + a01 * v1.y + a02 * v2.y);
            p.z = f2bf(a00 * v0.z + a01 * v1.z + a02 * v2.z);
            p.w = f2bf(a00 * v0.w + a01 * v1.w + a02 * v2.w);
            *(ushort4*)(&sA[ua][0] + qa * 4) = p;

            const long long base1 = base0 + 32ll * N_ITEM;
            v0 = *(const float4*)(icm + base1);
            v1 = *(const float4*)(icm + base1 + PLANE);
            v2 = *(const float4*)(icm + base1 + 2 * PLANE);
            p.x = f2bf(a10 * v0.x + a11 * v1.x + a12 * v2.x);
            p.y = f2bf(a10 * v0.y + a11 * v1.y + a12 * v2.y);
            p.z = f2bf(a10 * v0.z + a11 * v1.z + a12 * v2.z);
            p.w = f2bf(a10 * v0.w + a11 * v1.w + a12 * v2.w);
            *(ushort4*)(&sA[ua + 32][0] + qa * 4) = p;
        }
        // ---- stage B: 16B chunks of pre-transposed bf16 Bt ----
        {
            const unsigned short* g0 = Bt + (long long)db * N_ITEM + k0 + qb * 8;
            *(short8*)(&sB[db][0] + qb * 8) = *(const short8*)g0;
            const unsigned short* g1 = g0 + 64ll * N_ITEM;
            *(short8*)(&sB[db + 64][0] + qb * 8) = *(const short8*)g1;
        }
        __syncthreads();

        short8 af[2], bfr[4];
#pragma unroll
        for (int mi = 0; mi < 2; ++mi)
            af[mi] = *(const short8*)(&sA[wm * 32 + mi * 16 + la][0] + lb * 8);
#pragma unroll
        for (int ni = 0; ni < 4; ++ni)
            bfr[ni] = *(const short8*)(&sB[wn * 64 + ni * 16 + la][0] + lb * 8);
#pragma unroll
        for (int mi = 0; mi < 2; ++mi)
#pragma unroll
            for (int ni = 0; ni < 4; ++ni)
                acc[mi][ni] = __builtin_amdgcn_mfma_f32_16x16x32_bf16(
                    af[mi], bfr[ni], acc[mi][ni], 0, 0, 0);
        __syncthreads();
    }

#pragma unroll
    for (int mi = 0; mi < 2; ++mi)
#pragma unroll
        for (int ni = 0; ni < 4; ++ni)
#pragma unroll
            for (int r = 0; r < 4; ++r) {
                int row = m0 + wm * 32 + mi * 16 + lb * 4 + r;
                int col = wn * 64 + ni * 16 + la;
                unsafeAtomicAdd(uout + (long long)row * DD + col, acc[mi][ni][r]);
            }
}

// ---------------------------------------------------------------------------
extern "C" void kernel_launch(void* const* d_in, const int* in_sizes, int n_in,
                              void* d_out, int out_size, void* d_ws, size_t ws_size,
                              hipStream_t stream) {
    const float* ent  = (const float*)d_in[0];
    const float* item = (const float*)d_in[1];
    const float* usr  = (const float*)d_in[2];
    const float* rel  = (const float*)d_in[4];
    const int*   eidx = (const int*)d_in[5];
    const int*   etyp = (const int*)d_in[6];
    const float* eimp = (const float*)d_in[7];
    const int*   irow = (const int*)d_in[8];
    const int*   icol = (const int*)d_in[9];
    const float* ival = (const float*)d_in[10];
    const float* uclw = (const float*)d_in[13];
    const float* icm  = (const float*)d_in[14];

    float* out_ent = (float*)d_out;
    float* out_usr = out_ent + (size_t)N_ENT * DD;

    float* ws_att  = (float*)d_ws;                                  // 100000*32 f32 = 12.8MB
    float* ws_uatt = ws_att + (size_t)N_ENT * N_REL;                // 4096*3 f32
    unsigned short* ws_Bt = (unsigned short*)((char*)d_ws + (16u << 20)); // 128*8192 bf16 = 2MB

    (void)in_sizes; (void)n_in; (void)ws_size;

    hipMemsetAsync(d_out, 0, (size_t)out_size * sizeof(float), stream);

    k_ent_att<<<(N_ENT + 255) / 256, 256, 0, stream>>>(ent, rel, ws_att);
    k_item2<<<dim3(N_ITEM / 256, DD), 256, 0, stream>>>(item, rel, ws_Bt);
    k_user_att<<<N_USR / 256, 256, 0, stream>>>(usr, uclw, ws_uatt);
    k_edge_agg<<<N_EDGES / 4, 256, 0, stream>>>(ent, rel, eidx, etyp, eimp, ws_att, out_ent);
    k_user_gather<<<NNZ / 4, 256, 0, stream>>>(ent, irow, icol, ival, out_usr);
    k_disen_gemm<<<dim3(N_USR / BM, SPLITK), 256, 0, stream>>>(icm, ws_Bt, ws_uatt, out_usr);
}

// Round 2
// 727.842 us; speedup vs baseline: 1.3586x; 1.3586x over previous
//
#include <hip/hip_runtime.h>

#define N_ENT   100000
#define N_USR   4096
#define N_ITEM  8192
#define N_REL   32
#define N_CLS   3
#define DD      128
#define N_EDGES 800000
#define NNZ     204800

typedef __attribute__((ext_vector_type(8))) short short8;
typedef __attribute__((ext_vector_type(4))) float f32x4;

// manual f32 -> bf16 round-to-nearest-even (inputs finite)
static __device__ __forceinline__ unsigned short f2bf(float x) {
    unsigned int u = __builtin_bit_cast(unsigned int, x);
    u = (u + 0x7fffu + ((u >> 16) & 1u)) >> 16;
    return (unsigned short)u;
}

// ---------------- CSR build: histogram / scan / scatter --------------------
__global__ __launch_bounds__(256) void k_hist(const int* __restrict__ keys, int n,
                                              int* __restrict__ deg) {
    int i = blockIdx.x * 256 + threadIdx.x;
    if (i < n) atomicAdd(&deg[keys[i]], 1);
}

// single-block exclusive scan; writes row_ptr[0..n] and cursor[0..n-1]
__global__ __launch_bounds__(1024) void k_scan(const int* __restrict__ deg, int n,
                                               int* __restrict__ rowp,
                                               int* __restrict__ cur) {
    __shared__ int lds[1024];
    int t = threadIdx.x;
    int C = (n + 1023) >> 10;
    int lo = t * C, hi = min(lo + C, n);
    int s = 0;
    for (int i = lo; i < hi; ++i) s += deg[i];
    lds[t] = s;
    __syncthreads();
    for (int off = 1; off < 1024; off <<= 1) {
        int v = lds[t];
        int a = (t >= off) ? lds[t - off] : 0;
        __syncthreads();
        lds[t] = v + a;
        __syncthreads();
    }
    int run = (t == 0) ? 0 : lds[t - 1];
    for (int i = lo; i < hi; ++i) { rowp[i] = run; cur[i] = run; run += deg[i]; }
    if (t == 1023) rowp[n] = lds[1023];
}

__global__ __launch_bounds__(256) void k_scatter(const int* __restrict__ keys, int n,
                                                 int* __restrict__ cur,
                                                 int* __restrict__ perm) {
    int i = blockIdx.x * 256 + threadIdx.x;
    if (i < n) {
        int p = atomicAdd(&cur[keys[i]], 1);
        perm[p] = i;
    }
}

// ---------------- K1: ent_rel_att = softmax(entity_emb @ relation_emb^T) ----
__global__ __launch_bounds__(256) void k_ent_att(const float* __restrict__ ent,
                                                 const float* __restrict__ rel,
                                                 float* __restrict__ att) {
    __shared__ float srel[N_REL * DD];
    for (int i = threadIdx.x; i < N_REL * DD; i += 256) srel[i] = rel[i];
    __syncthreads();
    int e = blockIdx.x * 256 + threadIdx.x;
    if (e >= N_ENT) return;
    const float4* row = (const float4*)(ent + (size_t)e * DD);
    float acc[N_REL];
#pragma unroll
    for (int r = 0; r < N_REL; ++r) acc[r] = 0.f;
    for (int dq = 0; dq < DD / 4; ++dq) {
        float4 v = row[dq];
#pragma unroll
        for (int r = 0; r < N_REL; ++r) {
            float4 w = *(const float4*)&srel[r * DD + dq * 4];
            acc[r] += v.x * w.x + v.y * w.y + v.z * w.z + v.w * w.w;
        }
    }
    float m = acc[0];
#pragma unroll
    for (int r = 1; r < N_REL; ++r) m = fmaxf(m, acc[r]);
    float s = 0.f;
#pragma unroll
    for (int r = 0; r < N_REL; ++r) { acc[r] = __expf(acc[r] - m); s += acc[r]; }
    float inv = 1.f / s;
    float* o = att + (size_t)e * N_REL;
#pragma unroll
    for (int r = 0; r < N_REL; ++r) o[r] = acc[r] * inv;
}

// ---------------- K2: edge aggregation, CSR, wave per head -----------------
__global__ __launch_bounds__(256) void k_edge_agg_csr(const float* __restrict__ ent,
                                                      const float* __restrict__ rel,
                                                      const int* __restrict__ eidx,
                                                      const int* __restrict__ etyp,
                                                      const float* __restrict__ eimp,
                                                      const float* __restrict__ att,
                                                      const int* __restrict__ rowp,
                                                      const int* __restrict__ perm,
                                                      float* __restrict__ out) {
    __shared__ float srel[N_REL * DD];
    for (int i = threadIdx.x; i < N_REL * DD; i += 256) srel[i] = rel[i];
    __syncthreads();
    const int lane = threadIdx.x & 63;
    const int h = blockIdx.x * 4 + (threadIdx.x >> 6);   // 25000*4 == 100000 exactly
    const int beg = rowp[h], end = rowp[h + 1];
    // broadcast this head's att row into lanes 0..31, fetch via shfl
    float attv = (lane < N_REL) ? att[(size_t)h * N_REL + lane] : 0.f;
    float ax = 0.f, ay = 0.f;
    // depth-2 software pipeline: A = state for j, B(e only) = state for j+1
    int eA = (beg < end) ? perm[beg] : 0;
    int eB = (beg + 1 < end) ? perm[beg + 1] : 0;
    int tlA = eidx[N_EDGES + eA];
    int rA  = etyp[eA];
    float imA = eimp[eA];
    for (int j = beg; j < end; ++j) {
        int eC = (j + 2 < end) ? perm[j + 2] : 0;
        int tlB = eidx[N_EDGES + eB];
        int rB  = etyp[eB];
        float imB = eimp[eB];
        float s = __shfl(attv, rA) * imA;
        float2 b = ((const float2*)(ent + (size_t)tlA * DD))[lane];
        float2 a = ((const float2*)(srel + (size_t)rA * DD))[lane];
        ax = fmaf(a.x * b.x, s, ax);
        ay = fmaf(a.y * b.y, s, ay);
        tlA = tlB; rA = rB; imA = imB; eB = eC;
    }
    float2 o; o.x = ax; o.y = ay;
    ((float2*)(out + (size_t)h * DD))[lane] = o;
}

// ---------------- K3: user sparse gather, CSR, wave per user ---------------
__global__ __launch_bounds__(256) void k_user_gather_csr(const float* __restrict__ ent,
                                                         const int* __restrict__ cols,
                                                         const float* __restrict__ vals,
                                                         const int* __restrict__ rowp,
                                                         const int* __restrict__ perm,
                                                         float* __restrict__ uout) {
    const int lane = threadIdx.x & 63;
    const int u = blockIdx.x * 4 + (threadIdx.x >> 6);   // 1024*4 == 4096 exactly
    const int beg = rowp[u], end = rowp[u + 1];
    float ax = 0.f, ay = 0.f;
    int eA = (beg < end) ? perm[beg] : 0;
    int eB = (beg + 1 < end) ? perm[beg + 1] : 0;
    int cA = cols[eA];
    float vA = vals[eA];
    for (int j = beg; j < end; ++j) {
        int eC = (j + 2 < end) ? perm[j + 2] : 0;
        int cB = cols[eB];
        float vB = vals[eB];
        float2 b = ((const float2*)(ent + (size_t)cA * DD))[lane];
        ax = fmaf(b.x, vA, ax);
        ay = fmaf(b.y, vA, ay);
        cA = cB; vA = vB; eB = eC;
    }
    float2 o; o.x = ax; o.y = ay;
    ((float2*)(uout + (size_t)u * DD))[lane] = o;
}

// ---------------- K4b: Bt[d][i] = bf16(item[i][d] * sum_r rel[r][d]) -------
__global__ __launch_bounds__(256) void k_item2(const float* __restrict__ item,
                                               const float* __restrict__ rel,
                                               unsigned short* __restrict__ Bt) {
    int d = blockIdx.y;
    int i = blockIdx.x * 256 + threadIdx.x;
    float s = 0.f;
    for (int r = 0; r < N_REL; ++r) s += rel[r * DD + d];
    float v = item[(size_t)i * DD + d] * s;
    Bt[(size_t)d * N_ITEM + i] = f2bf(v);
}

// ---------------- K4c: user_cls_att = softmax(user_emb @ usr_cls_w^T) ------
__global__ __launch_bounds__(256) void k_user_att(const float* __restrict__ usr,
                                                  const float* __restrict__ w,
                                                  float* __restrict__ att) {
    __shared__ float sw[N_CLS * DD];
    for (int i = threadIdx.x; i < N_CLS * DD; i += 256) sw[i] = w[i];
    __syncthreads();
    int u = blockIdx.x * 256 + threadIdx.x;
    const float4* row = (const float4*)(usr + (size_t)u * DD);
    float acc[3] = {0.f, 0.f, 0.f};
    for (int dq = 0; dq < DD / 4; ++dq) {
        float4 v = row[dq];
#pragma unroll
        for (int c = 0; c < 3; ++c) {
            float4 ww = *(const float4*)&sw[c * DD + dq * 4];
            acc[c] += v.x * ww.x + v.y * ww.y + v.z * ww.z + v.w * ww.w;
        }
    }
    float m = fmaxf(acc[0], fmaxf(acc[1], acc[2]));
    float s = 0.f;
#pragma unroll
    for (int c = 0; c < 3; ++c) { acc[c] = __expf(acc[c] - m); s += acc[c]; }
    float inv = 1.f / s;
#pragma unroll
    for (int c = 0; c < 3; ++c) att[u * 3 + c] = acc[c] * inv;
}

// ---------------- K5: fused disen GEMM (split-K partial stores) ------------
// user_agg[u,d] += sum_i (sum_c att[u,c]*icm[c,u,i]) * item2[i,d]
#define BM 64
#define BK 32
#define SPLITK 8
#define KCH (N_ITEM / SPLITK)                 // 1024
#define PLANE ((long long)N_USR * N_ITEM)

__global__ __launch_bounds__(256) void k_disen_gemm(const float* __restrict__ icm,
                                                    const unsigned short* __restrict__ Bt,
                                                    const float* __restrict__ uatt,
                                                    float* __restrict__ part) {
    __shared__ unsigned short sA[BM][40];
    __shared__ unsigned short sB[DD][40];

    const int t  = threadIdx.x;
    const int m0 = blockIdx.x * BM;
    const long long k0b = (long long)blockIdx.y * KCH;

    const int ua = t >> 3;
    const int qa = t & 7;
    const float a00 = uatt[(m0 + ua) * 3 + 0];
    const float a01 = uatt[(m0 + ua) * 3 + 1];
    const float a02 = uatt[(m0 + ua) * 3 + 2];
    const float a10 = uatt[(m0 + ua + 32) * 3 + 0];
    const float a11 = uatt[(m0 + ua + 32) * 3 + 1];
    const float a12 = uatt[(m0 + ua + 32) * 3 + 2];

    const int db = t >> 2;
    const int qb = t & 3;

    const int lane = t & 63;
    const int wv = t >> 6;
    const int wm = wv >> 1, wn = wv & 1;
    const int la = lane & 15, lb = lane >> 4;

    f32x4 acc[2][4];
#pragma unroll
    for (int mi = 0; mi < 2; ++mi)
#pragma unroll
        for (int ni = 0; ni < 4; ++ni) {
            f32x4 z = {0.f, 0.f, 0.f, 0.f};
            acc[mi][ni] = z;
        }

    for (int kk = 0; kk < KCH; kk += BK) {
        const long long k0 = k0b + kk;
        {
            const long long base0 = (long long)(m0 + ua) * N_ITEM + k0 + qa * 4;
            float4 v0 = *(const float4*)(icm + base0);
            float4 v1 = *(const float4*)(icm + base0 + PLANE);
            float4 v2 = *(const float4*)(icm + base0 + 2 * PLANE);
            ushort4 p;
            p.x = f2bf(a00 * v0.x + a01 * v1.x + a02 * v2.x);
            p.y = f2bf(a00 * v0.y + a01 * v1.y + a02 * v2.y);
            p.z = f2bf(a00 * v0.z + a01 * v1.z + a02 * v2.z);
            p.w = f2bf(a00 * v0.w + a01 * v1.w + a02 * v2.w);
            *(ushort4*)(&sA[ua][0] + qa * 4) = p;

            const long long base1 = base0 + 32ll * N_ITEM;
            v0 = *(const float4*)(icm + base1);
            v1 = *(const float4*)(icm + base1 + PLANE);
            v2 = *(const float4*)(icm + base1 + 2 * PLANE);
            p.x = f2bf(a10 * v0.x + a11 * v1.x + a12 * v2.x);
            p.y = f2bf(a10 * v0.y + a11 * v1.y + a12 * v2.y);
            p.z = f2bf(a10 * v0.z + a11 * v1.z + a12 * v2.z);
            p.w = f2bf(a10 * v0.w + a11 * v1.w + a12 * v2.w);
            *(ushort4*)(&sA[ua + 32][0] + qa * 4) = p;
        }
        {
            const unsigned short* g0 = Bt + (long long)db * N_ITEM + k0 + qb * 8;
            *(short8*)(&sB[db][0] + qb * 8) = *(const short8*)g0;
            const unsigned short* g1 = g0 + 64ll * N_ITEM;
            *(short8*)(&sB[db + 64][0] + qb * 8) = *(const short8*)g1;
        }
        __syncthreads();

        short8 af[2], bfr[4];
#pragma unroll
        for (int mi = 0; mi < 2; ++mi)
            af[mi] = *(const short8*)(&sA[wm * 32 + mi * 16 + la][0] + lb * 8);
#pragma unroll
        for (int ni = 0; ni < 4; ++ni)
            bfr[ni] = *(const short8*)(&sB[wn * 64 + ni * 16 + la][0] + lb * 8);
#pragma unroll
        for (int mi = 0; mi < 2; ++mi)
#pragma unroll
            for (int ni = 0; ni < 4; ++ni)
                acc[mi][ni] = __builtin_amdgcn_mfma_f32_16x16x32_bf16(
                    af[mi], bfr[ni], acc[mi][ni], 0, 0, 0);
        __syncthreads();
    }

    float* pbase = part + (size_t)blockIdx.y * ((size_t)N_USR * DD);
#pragma unroll
    for (int mi = 0; mi < 2; ++mi)
#pragma unroll
        for (int ni = 0; ni < 4; ++ni)
#pragma unroll
            for (int r = 0; r < 4; ++r) {
                int row = m0 + wm * 32 + mi * 16 + lb * 4 + r;
                int col = wn * 64 + ni * 16 + la;
                pbase[(size_t)row * DD + col] = acc[mi][ni][r];
            }
}

// ---------------- K6: split-K reduce into user output ----------------------
__global__ __launch_bounds__(256) void k_finalize(const float* __restrict__ part,
                                                  float* __restrict__ uout) {
    int i = blockIdx.x * 256 + threadIdx.x;   // grid 2048 -> 524288 elems
    float s = uout[i];
#pragma unroll
    for (int k = 0; k < SPLITK; ++k) s += part[(size_t)k * N_USR * DD + i];
    uout[i] = s;
}

// ---------------------------------------------------------------------------
static constexpr size_t algn(size_t x) { return (x + 255) & ~(size_t)255; }

extern "C" void kernel_launch(void* const* d_in, const int* in_sizes, int n_in,
                              void* d_out, int out_size, void* d_ws, size_t ws_size,
                              hipStream_t stream) {
    const float* ent  = (const float*)d_in[0];
    const float* item = (const float*)d_in[1];
    const float* usr  = (const float*)d_in[2];
    const float* rel  = (const float*)d_in[4];
    const int*   eidx = (const int*)d_in[5];
    const int*   etyp = (const int*)d_in[6];
    const float* eimp = (const float*)d_in[7];
    const int*   irow = (const int*)d_in[8];
    const int*   icol = (const int*)d_in[9];
    const float* ival = (const float*)d_in[10];
    const float* uclw = (const float*)d_in[13];
    const float* icm  = (const float*)d_in[14];

    float* out_ent = (float*)d_out;
    float* out_usr = out_ent + (size_t)N_ENT * DD;

    // ---- workspace layout (~37.5 MB) ----
    char* w = (char*)d_ws;
    size_t o = 0;
    float* ws_att  = (float*)(w + o);  o = algn(o + (size_t)N_ENT * N_REL * 4);
    float* ws_uatt = (float*)(w + o);  o = algn(o + (size_t)N_USR * N_CLS * 4);
    unsigned short* ws_Bt = (unsigned short*)(w + o); o = algn(o + (size_t)DD * N_ITEM * 2);
    int* deg_e  = (int*)(w + o); o = algn(o + (size_t)N_ENT * 4);
    int* rowp_e = (int*)(w + o); o = algn(o + (size_t)(N_ENT + 1) * 4);
    int* cur_e  = (int*)(w + o); o = algn(o + (size_t)(N_ENT + 1) * 4);
    int* perm_e = (int*)(w + o); o = algn(o + (size_t)N_EDGES * 4);
    int* deg_u  = (int*)(w + o); o = algn(o + (size_t)N_USR * 4);
    int* rowp_u = (int*)(w + o); o = algn(o + (size_t)(N_USR + 1) * 4);
    int* cur_u  = (int*)(w + o); o = algn(o + (size_t)(N_USR + 1) * 4);
    int* perm_u = (int*)(w + o); o = algn(o + (size_t)NNZ * 4);
    float* part = (float*)(w + o); o = algn(o + (size_t)SPLITK * N_USR * DD * 4);

    (void)in_sizes; (void)n_in; (void)ws_size; (void)out_size;

    // ---- CSR build (edges by head, nnz by user) ----
    hipMemsetAsync(deg_e, 0, (size_t)N_ENT * 4, stream);
    hipMemsetAsync(deg_u, 0, (size_t)N_USR * 4, stream);
    k_hist<<<(N_EDGES + 255) / 256, 256, 0, stream>>>(eidx, N_EDGES, deg_e);
    k_hist<<<(NNZ + 255) / 256, 256, 0, stream>>>(irow, NNZ, deg_u);
    k_scan<<<1, 1024, 0, stream>>>(deg_e, N_ENT, rowp_e, cur_e);
    k_scan<<<1, 1024, 0, stream>>>(deg_u, N_USR, rowp_u, cur_u);
    k_scatter<<<(N_EDGES + 255) / 256, 256, 0, stream>>>(eidx, N_EDGES, cur_e, perm_e);
    k_scatter<<<(NNZ + 255) / 256, 256, 0, stream>>>(irow, NNZ, cur_u, perm_u);

    // ---- small precomputes ----
    k_ent_att<<<(N_ENT + 255) / 256, 256, 0, stream>>>(ent, rel, ws_att);
    k_item2<<<dim3(N_ITEM / 256, DD), 256, 0, stream>>>(item, rel, ws_Bt);
    k_user_att<<<N_USR / 256, 256, 0, stream>>>(usr, uclw, ws_uatt);

    // ---- main aggregations (no f32 atomics anywhere) ----
    k_edge_agg_csr<<<N_ENT / 4, 256, 0, stream>>>(ent, rel, eidx, etyp, eimp,
                                                  ws_att, rowp_e, perm_e, out_ent);
    k_user_gather_csr<<<N_USR / 4, 256, 0, stream>>>(ent, icol, ival,
                                                     rowp_u, perm_u, out_usr);
    k_disen_gemm<<<dim3(N_USR / BM, SPLITK), 256, 0, stream>>>(icm, ws_Bt, ws_uatt, part);
    k_finalize<<<(N_USR * DD) / 256, 256, 0, stream>>>(part, out_usr);
}

// Round 3
// 545.704 us; speedup vs baseline: 1.8120x; 1.3338x over previous
//
#include <hip/hip_runtime.h>

#define N_ENT   100000
#define N_USR   4096
#define N_ITEM  8192
#define N_REL   32
#define N_CLS   3
#define DD      128
#define N_EDGES 800000
#define NNZ     204800

typedef __attribute__((ext_vector_type(8))) short short8;
typedef __attribute__((ext_vector_type(4))) float f32x4;

static __device__ __forceinline__ unsigned short f2bf(float x) {
    unsigned int u = __builtin_bit_cast(unsigned int, x);
    u = (u + 0x7fffu + ((u >> 16) & 1u)) >> 16;
    return (unsigned short)u;
}

// ---------------- CSR build: histogram / hierarchical scan / scatter -------
__global__ __launch_bounds__(256) void k_hist(const int* __restrict__ keys, int n,
                                              int* __restrict__ deg) {
    int i = blockIdx.x * 256 + threadIdx.x;
    if (i < n) atomicAdd(&deg[keys[i]], 1);
}

// per-block exclusive scan of 1024 elements + block sums
__global__ __launch_bounds__(1024) void k_scan_local(const int* __restrict__ deg, int n,
                                                     int* __restrict__ excl,
                                                     int* __restrict__ bsum) {
    __shared__ int lds[1024];
    int t = threadIdx.x;
    int i = blockIdx.x * 1024 + t;
    int v = (i < n) ? deg[i] : 0;
    lds[t] = v;
    __syncthreads();
    for (int off = 1; off < 1024; off <<= 1) {
        int a = (t >= off) ? lds[t - off] : 0;
        __syncthreads();
        lds[t] += a;
        __syncthreads();
    }
    if (i < n) excl[i] = lds[t] - v;
    if (t == 1023) bsum[blockIdx.x] = lds[1023];
}

// exclusive scan of block sums in place (nb <= 1024)
__global__ __launch_bounds__(1024) void k_scan_bsum(int* __restrict__ bsum, int nb) {
    __shared__ int lds[1024];
    int t = threadIdx.x;
    int v = (t < nb) ? bsum[t] : 0;
    lds[t] = v;
    __syncthreads();
    for (int off = 1; off < 1024; off <<= 1) {
        int a = (t >= off) ? lds[t - off] : 0;
        __syncthreads();
        lds[t] += a;
        __syncthreads();
    }
    if (t < nb) bsum[t] = lds[t] - v;
}

__global__ __launch_bounds__(1024) void k_scan_add(const int* __restrict__ excl,
                                                   const int* __restrict__ bsum, int n,
                                                   int ntot, int* __restrict__ rowp,
                                                   int* __restrict__ cur) {
    int i = blockIdx.x * 1024 + threadIdx.x;
    if (i < n) {
        int v = excl[i] + bsum[blockIdx.x];
        rowp[i] = v;
        cur[i] = v;
    }
    if (i == 0) rowp[n] = ntot;
}

__global__ __launch_bounds__(256) void k_scatter(const int* __restrict__ keys, int n,
                                                 int* __restrict__ cur,
                                                 int* __restrict__ perm) {
    int i = blockIdx.x * 256 + threadIdx.x;
    if (i < n) {
        int p = atomicAdd(&cur[keys[i]], 1);
        perm[p] = i;
    }
}

// ---------------- K1: ent_rel_att = softmax(entity_emb @ relation_emb^T) ----
__global__ __launch_bounds__(256) void k_ent_att(const float* __restrict__ ent,
                                                 const float* __restrict__ rel,
                                                 float* __restrict__ att) {
    __shared__ float srel[N_REL * DD];
    for (int i = threadIdx.x; i < N_REL * DD; i += 256) srel[i] = rel[i];
    __syncthreads();
    int e = blockIdx.x * 256 + threadIdx.x;
    if (e >= N_ENT) return;
    const float4* row = (const float4*)(ent + (size_t)e * DD);
    float acc[N_REL];
#pragma unroll
    for (int r = 0; r < N_REL; ++r) acc[r] = 0.f;
    for (int dq = 0; dq < DD / 4; ++dq) {
        float4 v = row[dq];
#pragma unroll
        for (int r = 0; r < N_REL; ++r) {
            float4 w = *(const float4*)&srel[r * DD + dq * 4];
            acc[r] += v.x * w.x + v.y * w.y + v.z * w.z + v.w * w.w;
        }
    }
    float m = acc[0];
#pragma unroll
    for (int r = 1; r < N_REL; ++r) m = fmaxf(m, acc[r]);
    float s = 0.f;
#pragma unroll
    for (int r = 0; r < N_REL; ++r) { acc[r] = __expf(acc[r] - m); s += acc[r]; }
    float inv = 1.f / s;
    float* o = att + (size_t)e * N_REL;
#pragma unroll
    for (int r = 0; r < N_REL; ++r) o[r] = acc[r] * inv;
}

// ---------------- pack per-edge payload into CSR order ---------------------
// pack[p] = { tail | (rtype<<24), bits(att[head,rtype]*imp) }
__global__ __launch_bounds__(256) void k_edge_pack(const int* __restrict__ eidx,
                                                   const int* __restrict__ etyp,
                                                   const float* __restrict__ eimp,
                                                   const float* __restrict__ att,
                                                   const int* __restrict__ perm,
                                                   int2* __restrict__ pack) {
    int p = blockIdx.x * 256 + threadIdx.x;
    if (p >= N_EDGES) return;
    int e = perm[p];
    int h = eidx[e], tl = eidx[N_EDGES + e], r = etyp[e];
    float s = att[(size_t)h * N_REL + r] * eimp[e];
    int2 pk;
    pk.x = tl | (r << 24);
    pk.y = __float_as_int(s);
    pack[p] = pk;
}

__global__ __launch_bounds__(256) void k_user_pack(const int* __restrict__ cols,
                                                   const float* __restrict__ vals,
                                                   const int* __restrict__ perm,
                                                   int2* __restrict__ pack) {
    int p = blockIdx.x * 256 + threadIdx.x;
    if (p >= NNZ) return;
    int e = perm[p];
    int2 pk;
    pk.x = cols[e];
    pk.y = __float_as_int(vals[e]);
    pack[p] = pk;
}

// ---------------- K2: edge aggregation, packed CSR, wave per head ----------
__global__ __launch_bounds__(256) void k_edge_agg2(const float* __restrict__ ent,
                                                   const float* __restrict__ rel,
                                                   const int2* __restrict__ pack,
                                                   const int* __restrict__ rowp,
                                                   float* __restrict__ out) {
    __shared__ float srel[N_REL * DD];
    for (int i = threadIdx.x; i < N_REL * DD; i += 256) srel[i] = rel[i];
    __syncthreads();
    const int lane = threadIdx.x & 63;
    const int h = blockIdx.x * 4 + (threadIdx.x >> 6);   // 25000*4 == 100000
    const int beg = rowp[h], end = rowp[h + 1];
    float ax = 0.f, ay = 0.f;
    int2 pkA = {0, 0};
    if (beg < end) pkA = pack[beg];
    for (int j = beg; j < end; ++j) {
        int2 pkB = (j + 1 < end) ? pack[j + 1] : pkA;
        int tl = pkA.x & 0xFFFFFF;
        int r  = ((unsigned)pkA.x) >> 24;
        float s = __int_as_float(pkA.y);
        float2 b = ((const float2*)(ent + (size_t)tl * DD))[lane];
        float2 a = ((const float2*)(srel + (size_t)r * DD))[lane];
        ax = fmaf(a.x * b.x, s, ax);
        ay = fmaf(a.y * b.y, s, ay);
        pkA = pkB;
    }
    float2 o; o.x = ax; o.y = ay;
    ((float2*)(out + (size_t)h * DD))[lane] = o;
}

// ---------------- K3: user sparse gather, packed CSR, wave per user --------
__global__ __launch_bounds__(256) void k_user_gather2(const float* __restrict__ ent,
                                                      const int2* __restrict__ pack,
                                                      const int* __restrict__ rowp,
                                                      float* __restrict__ uout) {
    const int lane = threadIdx.x & 63;
    const int u = blockIdx.x * 4 + (threadIdx.x >> 6);   // 1024*4 == 4096
    const int beg = rowp[u], end = rowp[u + 1];
    float ax = 0.f, ay = 0.f;
    int2 pkA = {0, 0};
    if (beg < end) pkA = pack[beg];
    for (int j = beg; j < end; ++j) {
        int2 pkB = (j + 1 < end) ? pack[j + 1] : pkA;
        int c = pkA.x;
        float v = __int_as_float(pkA.y);
        float2 b = ((const float2*)(ent + (size_t)c * DD))[lane];
        ax = fmaf(b.x, v, ax);
        ay = fmaf(b.y, v, ay);
        pkA = pkB;
    }
    float2 o; o.x = ax; o.y = ay;
    ((float2*)(uout + (size_t)u * DD))[lane] = o;
}

// ---------------- K4b: Bt[d][i] = bf16(item[i][d]*ssum[d]) — tiled transpose
__global__ __launch_bounds__(256) void k_item2_t(const float* __restrict__ item,
                                                 const float* __restrict__ rel,
                                                 unsigned short* __restrict__ Bt) {
    __shared__ float tile[32][33];
    __shared__ float ssum[32];
    const int tx = threadIdx.x & 31, ty = threadIdx.x >> 5;   // ty 0..7
    const int i0 = blockIdx.x * 32, d0 = blockIdx.y * 32;
    if (threadIdx.x < 32) {
        float s = 0.f;
        for (int r = 0; r < N_REL; ++r) s += rel[r * DD + d0 + threadIdx.x];
        ssum[threadIdx.x] = s;
    }
#pragma unroll
    for (int rr = 0; rr < 4; ++rr)
        tile[ty + 8 * rr][tx] = item[(size_t)(i0 + ty + 8 * rr) * DD + d0 + tx];
    __syncthreads();
#pragma unroll
    for (int rr = 0; rr < 4; ++rr) {
        int d = d0 + ty + 8 * rr;
        Bt[(size_t)d * N_ITEM + i0 + tx] = f2bf(tile[tx][ty + 8 * rr] * ssum[ty + 8 * rr]);
    }
}

// ---------------- K4c: user_cls_att = softmax(user_emb @ usr_cls_w^T) ------
__global__ __launch_bounds__(256) void k_user_att(const float* __restrict__ usr,
                                                  const float* __restrict__ w,
                                                  float* __restrict__ att) {
    __shared__ float sw[N_CLS * DD];
    for (int i = threadIdx.x; i < N_CLS * DD; i += 256) sw[i] = w[i];
    __syncthreads();
    int u = blockIdx.x * 256 + threadIdx.x;
    const float4* row = (const float4*)(usr + (size_t)u * DD);
    float acc[3] = {0.f, 0.f, 0.f};
    for (int dq = 0; dq < DD / 4; ++dq) {
        float4 v = row[dq];
#pragma unroll
        for (int c = 0; c < 3; ++c) {
            float4 ww = *(const float4*)&sw[c * DD + dq * 4];
            acc[c] += v.x * ww.x + v.y * ww.y + v.z * ww.z + v.w * ww.w;
        }
    }
    float m = fmaxf(acc[0], fmaxf(acc[1], acc[2]));
    float s = 0.f;
#pragma unroll
    for (int c = 0; c < 3; ++c) { acc[c] = __expf(acc[c] - m); s += acc[c]; }
    float inv = 1.f / s;
#pragma unroll
    for (int c = 0; c < 3; ++c) att[u * 3 + c] = acc[c] * inv;
}

// ---------------- K5: fused disen GEMM (split-K partial stores) ------------
#define BM 64
#define BK 32
#define SPLITK 8
#define KCH (N_ITEM / SPLITK)
#define PLANE ((long long)N_USR * N_ITEM)

__global__ __launch_bounds__(256) void k_disen_gemm(const float* __restrict__ icm,
                                                    const unsigned short* __restrict__ Bt,
                                                    const float* __restrict__ uatt,
                                                    float* __restrict__ part) {
    __shared__ unsigned short sA[BM][40];
    __shared__ unsigned short sB[DD][40];

    const int t  = threadIdx.x;
    const int m0 = blockIdx.x * BM;
    const long long k0b = (long long)blockIdx.y * KCH;

    const int ua = t >> 3;
    const int qa = t & 7;
    const float a00 = uatt[(m0 + ua) * 3 + 0];
    const float a01 = uatt[(m0 + ua) * 3 + 1];
    const float a02 = uatt[(m0 + ua) * 3 + 2];
    const float a10 = uatt[(m0 + ua + 32) * 3 + 0];
    const float a11 = uatt[(m0 + ua + 32) * 3 + 1];
    const float a12 = uatt[(m0 + ua + 32) * 3 + 2];

    const int db = t >> 2;
    const int qb = t & 3;

    const int lane = t & 63;
    const int wv = t >> 6;
    const int wm = wv >> 1, wn = wv & 1;
    const int la = lane & 15, lb = lane >> 4;

    f32x4 acc[2][4];
#pragma unroll
    for (int mi = 0; mi < 2; ++mi)
#pragma unroll
        for (int ni = 0; ni < 4; ++ni) {
            f32x4 z = {0.f, 0.f, 0.f, 0.f};
            acc[mi][ni] = z;
        }

    for (int kk = 0; kk < KCH; kk += BK) {
        const long long k0 = k0b + kk;
        {
            const long long base0 = (long long)(m0 + ua) * N_ITEM + k0 + qa * 4;
            float4 v0 = *(const float4*)(icm + base0);
            float4 v1 = *(const float4*)(icm + base0 + PLANE);
            float4 v2 = *(const float4*)(icm + base0 + 2 * PLANE);
            ushort4 p;
            p.x = f2bf(a00 * v0.x + a01 * v1.x + a02 * v2.x);
            p.y = f2bf(a00 * v0.y + a01 * v1.y + a02 * v2.y);
            p.z = f2bf(a00 * v0.z + a01 * v1.z + a02 * v2.z);
            p.w = f2bf(a00 * v0.w + a01 * v1.w + a02 * v2.w);
            *(ushort4*)(&sA[ua][0] + qa * 4) = p;

            const long long base1 = base0 + 32ll * N_ITEM;
            v0 = *(const float4*)(icm + base1);
            v1 = *(const float4*)(icm + base1 + PLANE);
            v2 = *(const float4*)(icm + base1 + 2 * PLANE);
            p.x = f2bf(a10 * v0.x + a11 * v1.x + a12 * v2.x);
            p.y = f2bf(a10 * v0.y + a11 * v1.y + a12 * v2.y);
            p.z = f2bf(a10 * v0.z + a11 * v1.z + a12 * v2.z);
            p.w = f2bf(a10 * v0.w + a11 * v1.w + a12 * v2.w);
            *(ushort4*)(&sA[ua + 32][0] + qa * 4) = p;
        }
        {
            const unsigned short* g0 = Bt + (long long)db * N_ITEM + k0 + qb * 8;
            *(short8*)(&sB[db][0] + qb * 8) = *(const short8*)g0;
            const unsigned short* g1 = g0 + 64ll * N_ITEM;
            *(short8*)(&sB[db + 64][0] + qb * 8) = *(const short8*)g1;
        }
        __syncthreads();

        short8 af[2], bfr[4];
#pragma unroll
        for (int mi = 0; mi < 2; ++mi)
            af[mi] = *(const short8*)(&sA[wm * 32 + mi * 16 + la][0] + lb * 8);
#pragma unroll
        for (int ni = 0; ni < 4; ++ni)
            bfr[ni] = *(const short8*)(&sB[wn * 64 + ni * 16 + la][0] + lb * 8);
#pragma unroll
        for (int mi = 0; mi < 2; ++mi)
#pragma unroll
            for (int ni = 0; ni < 4; ++ni)
                acc[mi][ni] = __builtin_amdgcn_mfma_f32_16x16x32_bf16(
                    af[mi], bfr[ni], acc[mi][ni], 0, 0, 0);
        __syncthreads();
    }

    float* pbase = part + (size_t)blockIdx.y * ((size_t)N_USR * DD);
#pragma unroll
    for (int mi = 0; mi < 2; ++mi)
#pragma unroll
        for (int ni = 0; ni < 4; ++ni)
#pragma unroll
            for (int r = 0; r < 4; ++r) {
                int row = m0 + wm * 32 + mi * 16 + lb * 4 + r;
                int col = wn * 64 + ni * 16 + la;
                pbase[(size_t)row * DD + col] = acc[mi][ni][r];
            }
}

__global__ __launch_bounds__(256) void k_finalize(const float* __restrict__ part,
                                                  float* __restrict__ uout) {
    int i = blockIdx.x * 256 + threadIdx.x;
    float s = uout[i];
#pragma unroll
    for (int k = 0; k < SPLITK; ++k) s += part[(size_t)k * N_USR * DD + i];
    uout[i] = s;
}

// ---------------------------------------------------------------------------
static constexpr size_t algn(size_t x) { return (x + 255) & ~(size_t)255; }

extern "C" void kernel_launch(void* const* d_in, const int* in_sizes, int n_in,
                              void* d_out, int out_size, void* d_ws, size_t ws_size,
                              hipStream_t stream) {
    const float* ent  = (const float*)d_in[0];
    const float* item = (const float*)d_in[1];
    const float* usr  = (const float*)d_in[2];
    const float* rel  = (const float*)d_in[4];
    const int*   eidx = (const int*)d_in[5];
    const int*   etyp = (const int*)d_in[6];
    const float* eimp = (const float*)d_in[7];
    const int*   irow = (const int*)d_in[8];
    const int*   icol = (const int*)d_in[9];
    const float* ival = (const float*)d_in[10];
    const float* uclw = (const float*)d_in[13];
    const float* icm  = (const float*)d_in[14];

    float* out_ent = (float*)d_out;
    float* out_usr = out_ent + (size_t)N_ENT * DD;

    char* w = (char*)d_ws;
    size_t o = 0;
    float* ws_att  = (float*)(w + o);  o = algn(o + (size_t)N_ENT * N_REL * 4);
    float* ws_uatt = (float*)(w + o);  o = algn(o + (size_t)N_USR * N_CLS * 4);
    unsigned short* ws_Bt = (unsigned short*)(w + o); o = algn(o + (size_t)DD * N_ITEM * 2);
    int* deg_e  = (int*)(w + o); o = algn(o + (size_t)N_ENT * 4);
    int* rowp_e = (int*)(w + o); o = algn(o + (size_t)(N_ENT + 1) * 4);
    int* cur_e  = (int*)(w + o); o = algn(o + (size_t)(N_ENT + 1) * 4);
    int* excl_e = (int*)(w + o); o = algn(o + (size_t)N_ENT * 4);
    int* bsum_e = (int*)(w + o); o = algn(o + 1024 * 4);
    int* perm_e = (int*)(w + o); o = algn(o + (size_t)N_EDGES * 4);
    int* deg_u  = (int*)(w + o); o = algn(o + (size_t)N_USR * 4);
    int* rowp_u = (int*)(w + o); o = algn(o + (size_t)(N_USR + 1) * 4);
    int* cur_u  = (int*)(w + o); o = algn(o + (size_t)(N_USR + 1) * 4);
    int* excl_u = (int*)(w + o); o = algn(o + (size_t)N_USR * 4);
    int* bsum_u = (int*)(w + o); o = algn(o + 1024 * 4);
    int* perm_u = (int*)(w + o); o = algn(o + (size_t)NNZ * 4);
    int2* pack_e = (int2*)(w + o); o = algn(o + (size_t)N_EDGES * 8);
    int2* pack_u = (int2*)(w + o); o = algn(o + (size_t)NNZ * 8);
    float* part  = (float*)(w + o); o = algn(o + (size_t)SPLITK * N_USR * DD * 4);

    (void)in_sizes; (void)n_in; (void)ws_size; (void)out_size;

    const int nb_e = (N_ENT + 1023) / 1024;   // 98
    const int nb_u = (N_USR + 1023) / 1024;   // 4

    // ---- CSR build ----
    hipMemsetAsync(deg_e, 0, (size_t)N_ENT * 4, stream);
    hipMemsetAsync(deg_u, 0, (size_t)N_USR * 4, stream);
    k_hist<<<(N_EDGES + 255) / 256, 256, 0, stream>>>(eidx, N_EDGES, deg_e);
    k_hist<<<(NNZ + 255) / 256, 256, 0, stream>>>(irow, NNZ, deg_u);
    k_scan_local<<<nb_e, 1024, 0, stream>>>(deg_e, N_ENT, excl_e, bsum_e);
    k_scan_local<<<nb_u, 1024, 0, stream>>>(deg_u, N_USR, excl_u, bsum_u);
    k_scan_bsum<<<1, 1024, 0, stream>>>(bsum_e, nb_e);
    k_scan_bsum<<<1, 1024, 0, stream>>>(bsum_u, nb_u);
    k_scan_add<<<nb_e, 1024, 0, stream>>>(excl_e, bsum_e, N_ENT, N_EDGES, rowp_e, cur_e);
    k_scan_add<<<nb_u, 1024, 0, stream>>>(excl_u, bsum_u, N_USR, NNZ, rowp_u, cur_u);
    k_scatter<<<(N_EDGES + 255) / 256, 256, 0, stream>>>(eidx, N_EDGES, cur_e, perm_e);
    k_scatter<<<(NNZ + 255) / 256, 256, 0, stream>>>(irow, NNZ, cur_u, perm_u);

    // ---- small precomputes ----
    k_ent_att<<<(N_ENT + 255) / 256, 256, 0, stream>>>(ent, rel, ws_att);
    k_item2_t<<<dim3(N_ITEM / 32, DD / 32), 256, 0, stream>>>(item, rel, ws_Bt);
    k_user_att<<<N_USR / 256, 256, 0, stream>>>(usr, uclw, ws_uatt);
    k_edge_pack<<<(N_EDGES + 255) / 256, 256, 0, stream>>>(eidx, etyp, eimp, ws_att,
                                                           perm_e, pack_e);
    k_user_pack<<<(NNZ + 255) / 256, 256, 0, stream>>>(icol, ival, perm_u, pack_u);

    // ---- main aggregations ----
    k_edge_agg2<<<N_ENT / 4, 256, 0, stream>>>(ent, rel, pack_e, rowp_e, out_ent);
    k_user_gather2<<<N_USR / 4, 256, 0, stream>>>(ent, pack_u, rowp_u, out_usr);
    k_disen_gemm<<<dim3(N_USR / BM, SPLITK), 256, 0, stream>>>(icm, ws_Bt, ws_uatt, part);
    k_finalize<<<(N_USR * DD) / 256, 256, 0, stream>>>(part, out_usr);
}

// Round 4
// 403.300 us; speedup vs baseline: 2.4518x; 1.3531x over previous
//
#include <hip/hip_runtime.h>

#define N_ENT   100000
#define N_USR   4096
#define N_ITEM  8192
#define N_REL   32
#define N_CLS   3
#define DD      128
#define N_EDGES 800000
#define NNZ     204800

typedef __attribute__((ext_vector_type(8))) short short8;
typedef __attribute__((ext_vector_type(4))) float f32x4;

static __device__ __forceinline__ unsigned short f2bf(float x) {
    unsigned int u = __builtin_bit_cast(unsigned int, x);
    u = (u + 0x7fffu + ((u >> 16) & 1u)) >> 16;
    return (unsigned short)u;
}

// ---------------- CSR build ------------------------------------------------
__global__ __launch_bounds__(256) void k_hist_all(const int* __restrict__ ekeys,
                                                  const int* __restrict__ ukeys,
                                                  int* __restrict__ deg_e,
                                                  int* __restrict__ deg_u) {
    int i = blockIdx.x * 256 + threadIdx.x;
    if (i < N_EDGES) atomicAdd(&deg_e[ekeys[i]], 1);
    if (i < NNZ) atomicAdd(&deg_u[ukeys[i]], 1);
}

__global__ __launch_bounds__(1024) void k_scan_local(const int* __restrict__ deg, int n,
                                                     int* __restrict__ excl,
                                                     int* __restrict__ bsum) {
    __shared__ int lds[1024];
    int t = threadIdx.x;
    int i = blockIdx.x * 1024 + t;
    int v = (i < n) ? deg[i] : 0;
    lds[t] = v;
    __syncthreads();
    for (int off = 1; off < 1024; off <<= 1) {
        int a = (t >= off) ? lds[t - off] : 0;
        __syncthreads();
        lds[t] += a;
        __syncthreads();
    }
    if (i < n) excl[i] = lds[t] - v;
    if (t == 1023) bsum[blockIdx.x] = lds[1023];
}

__global__ __launch_bounds__(1024) void k_scan_bsum(int* __restrict__ bsum, int nb) {
    __shared__ int lds[1024];
    int t = threadIdx.x;
    int v = (t < nb) ? bsum[t] : 0;
    lds[t] = v;
    __syncthreads();
    for (int off = 1; off < 1024; off <<= 1) {
        int a = (t >= off) ? lds[t - off] : 0;
        __syncthreads();
        lds[t] += a;
        __syncthreads();
    }
    if (t < nb) bsum[t] = lds[t] - v;
}

__global__ __launch_bounds__(1024) void k_scan_add(const int* __restrict__ excl,
                                                   const int* __restrict__ bsum, int n,
                                                   int ntot, int* __restrict__ rowp,
                                                   int* __restrict__ cur) {
    int i = blockIdx.x * 1024 + threadIdx.x;
    if (i < n) {
        int v = excl[i] + bsum[blockIdx.x];
        rowp[i] = v;
        cur[i] = v;
    }
    if (i == 0) rowp[n] = ntot;
}

// ---------------- K1: ent_rel_att = softmax(entity_emb @ relation_emb^T) ----
__global__ __launch_bounds__(256) void k_ent_att(const float* __restrict__ ent,
                                                 const float* __restrict__ rel,
                                                 float* __restrict__ att) {
    __shared__ float srel[N_REL * DD];
    for (int i = threadIdx.x; i < N_REL * DD; i += 256) srel[i] = rel[i];
    __syncthreads();
    int e = blockIdx.x * 256 + threadIdx.x;
    if (e >= N_ENT) return;
    const float4* row = (const float4*)(ent + (size_t)e * DD);
    float acc[N_REL];
#pragma unroll
    for (int r = 0; r < N_REL; ++r) acc[r] = 0.f;
    for (int dq = 0; dq < DD / 4; ++dq) {
        float4 v = row[dq];
#pragma unroll
        for (int r = 0; r < N_REL; ++r) {
            float4 w = *(const float4*)&srel[r * DD + dq * 4];
            acc[r] += v.x * w.x + v.y * w.y + v.z * w.z + v.w * w.w;
        }
    }
    float m = acc[0];
#pragma unroll
    for (int r = 1; r < N_REL; ++r) m = fmaxf(m, acc[r]);
    float s = 0.f;
#pragma unroll
    for (int r = 0; r < N_REL; ++r) { acc[r] = __expf(acc[r] - m); s += acc[r]; }
    float inv = 1.f / s;
    float* o = att + (size_t)e * N_REL;
#pragma unroll
    for (int r = 0; r < N_REL; ++r) o[r] = acc[r] * inv;
}

// ---------------- fused scatter+pack (perm eliminated) ---------------------
__global__ __launch_bounds__(256) void k_scatter_pack_e(const int* __restrict__ eidx,
                                                        const int* __restrict__ etyp,
                                                        const float* __restrict__ eimp,
                                                        const float* __restrict__ att,
                                                        int* __restrict__ cur,
                                                        int2* __restrict__ pack) {
    int i = blockIdx.x * 256 + threadIdx.x;
    if (i >= N_EDGES) return;
    int h = eidx[i], tl = eidx[N_EDGES + i], r = etyp[i];
    float s = att[(size_t)h * N_REL + r] * eimp[i];
    int p = atomicAdd(&cur[h], 1);
    int2 pk;
    pk.x = tl | (r << 24);
    pk.y = __float_as_int(s);
    pack[p] = pk;
}

__global__ __launch_bounds__(256) void k_scatter_pack_u(const int* __restrict__ rows,
                                                        const int* __restrict__ cols,
                                                        const float* __restrict__ vals,
                                                        int* __restrict__ cur,
                                                        int2* __restrict__ pack) {
    int i = blockIdx.x * 256 + threadIdx.x;
    if (i >= NNZ) return;
    int p = atomicAdd(&cur[rows[i]], 1);
    int2 pk;
    pk.x = cols[i];
    pk.y = __float_as_int(vals[i]);
    pack[p] = pk;
}

// ---------------- K2: edge aggregation, 4-deep pipelined gather ------------
__global__ __launch_bounds__(256) void k_edge_agg2(const float* __restrict__ ent,
                                                   const float* __restrict__ rel,
                                                   const int2* __restrict__ pack,
                                                   const int* __restrict__ rowp,
                                                   float* __restrict__ out) {
    __shared__ float srel[N_REL * DD];
    for (int i = threadIdx.x; i < N_REL * DD; i += 256) srel[i] = rel[i];
    __syncthreads();
    const int lane = threadIdx.x & 63;
    const int h = blockIdx.x * 4 + (threadIdx.x >> 6);   // 25000*4 == 100000
    const int beg = rowp[h], end = rowp[h + 1];
    float ax = 0.f, ay = 0.f;
    int j = beg;
    for (; j + 4 <= end; j += 4) {
        int2 p0 = pack[j], p1 = pack[j + 1], p2 = pack[j + 2], p3 = pack[j + 3];
        float2 b0 = ((const float2*)(ent + (size_t)(p0.x & 0xFFFFFF) * DD))[lane];
        float2 b1 = ((const float2*)(ent + (size_t)(p1.x & 0xFFFFFF) * DD))[lane];
        float2 b2 = ((const float2*)(ent + (size_t)(p2.x & 0xFFFFFF) * DD))[lane];
        float2 b3 = ((const float2*)(ent + (size_t)(p3.x & 0xFFFFFF) * DD))[lane];
        float2 a0 = ((const float2*)(srel + (size_t)(((unsigned)p0.x) >> 24) * DD))[lane];
        float2 a1 = ((const float2*)(srel + (size_t)(((unsigned)p1.x) >> 24) * DD))[lane];
        float2 a2 = ((const float2*)(srel + (size_t)(((unsigned)p2.x) >> 24) * DD))[lane];
        float2 a3 = ((const float2*)(srel + (size_t)(((unsigned)p3.x) >> 24) * DD))[lane];
        float s0 = __int_as_float(p0.y), s1 = __int_as_float(p1.y);
        float s2 = __int_as_float(p2.y), s3 = __int_as_float(p3.y);
        ax = fmaf(a0.x * b0.x, s0, ax); ay = fmaf(a0.y * b0.y, s0, ay);
        ax = fmaf(a1.x * b1.x, s1, ax); ay = fmaf(a1.y * b1.y, s1, ay);
        ax = fmaf(a2.x * b2.x, s2, ax); ay = fmaf(a2.y * b2.y, s2, ay);
        ax = fmaf(a3.x * b3.x, s3, ax); ay = fmaf(a3.y * b3.y, s3, ay);
    }
    for (; j < end; ++j) {
        int2 pk = pack[j];
        int tl = pk.x & 0xFFFFFF;
        int r  = ((unsigned)pk.x) >> 24;
        float s = __int_as_float(pk.y);
        float2 b = ((const float2*)(ent + (size_t)tl * DD))[lane];
        float2 a = ((const float2*)(srel + (size_t)r * DD))[lane];
        ax = fmaf(a.x * b.x, s, ax);
        ay = fmaf(a.y * b.y, s, ay);
    }
    float2 o; o.x = ax; o.y = ay;
    ((float2*)(out + (size_t)h * DD))[lane] = o;
}

// ---------------- K3: user sparse gather, 4-deep pipelined -----------------
__global__ __launch_bounds__(256) void k_user_gather2(const float* __restrict__ ent,
                                                      const int2* __restrict__ pack,
                                                      const int* __restrict__ rowp,
                                                      float* __restrict__ uout) {
    const int lane = threadIdx.x & 63;
    const int u = blockIdx.x * 4 + (threadIdx.x >> 6);   // 1024*4 == 4096
    const int beg = rowp[u], end = rowp[u + 1];
    float ax = 0.f, ay = 0.f;
    int j = beg;
    for (; j + 4 <= end; j += 4) {
        int2 p0 = pack[j], p1 = pack[j + 1], p2 = pack[j + 2], p3 = pack[j + 3];
        float2 b0 = ((const float2*)(ent + (size_t)p0.x * DD))[lane];
        float2 b1 = ((const float2*)(ent + (size_t)p1.x * DD))[lane];
        float2 b2 = ((const float2*)(ent + (size_t)p2.x * DD))[lane];
        float2 b3 = ((const float2*)(ent + (size_t)p3.x * DD))[lane];
        float s0 = __int_as_float(p0.y), s1 = __int_as_float(p1.y);
        float s2 = __int_as_float(p2.y), s3 = __int_as_float(p3.y);
        ax = fmaf(b0.x, s0, ax); ay = fmaf(b0.y, s0, ay);
        ax = fmaf(b1.x, s1, ax); ay = fmaf(b1.y, s1, ay);
        ax = fmaf(b2.x, s2, ax); ay = fmaf(b2.y, s2, ay);
        ax = fmaf(b3.x, s3, ax); ay = fmaf(b3.y, s3, ay);
    }
    for (; j < end; ++j) {
        int2 pk = pack[j];
        float v = __int_as_float(pk.y);
        float2 b = ((const float2*)(ent + (size_t)pk.x * DD))[lane];
        ax = fmaf(b.x, v, ax);
        ay = fmaf(b.y, v, ay);
    }
    float2 o; o.x = ax; o.y = ay;
    ((float2*)(uout + (size_t)u * DD))[lane] = o;
}

// ---------------- K4b: Bt[d][i] = bf16(item[i][d]*ssum[d]), tiled ----------
__global__ __launch_bounds__(256) void k_item2_t(const float* __restrict__ item,
                                                 const float* __restrict__ rel,
                                                 unsigned short* __restrict__ Bt) {
    __shared__ float tile[32][33];
    __shared__ float ssum[32];
    const int tx = threadIdx.x & 31, ty = threadIdx.x >> 5;
    const int i0 = blockIdx.x * 32, d0 = blockIdx.y * 32;
    if (threadIdx.x < 32) {
        float s = 0.f;
        for (int r = 0; r < N_REL; ++r) s += rel[r * DD + d0 + threadIdx.x];
        ssum[threadIdx.x] = s;
    }
#pragma unroll
    for (int rr = 0; rr < 4; ++rr)
        tile[ty + 8 * rr][tx] = item[(size_t)(i0 + ty + 8 * rr) * DD + d0 + tx];
    __syncthreads();
#pragma unroll
    for (int rr = 0; rr < 4; ++rr) {
        int d = d0 + ty + 8 * rr;
        Bt[(size_t)d * N_ITEM + i0 + tx] = f2bf(tile[tx][ty + 8 * rr] * ssum[ty + 8 * rr]);
    }
}

// ---------------- K4c: user_cls_att --------------------------------------
__global__ __launch_bounds__(256) void k_user_att(const float* __restrict__ usr,
                                                  const float* __restrict__ w,
                                                  float* __restrict__ att) {
    __shared__ float sw[N_CLS * DD];
    for (int i = threadIdx.x; i < N_CLS * DD; i += 256) sw[i] = w[i];
    __syncthreads();
    int u = blockIdx.x * 256 + threadIdx.x;
    const float4* row = (const float4*)(usr + (size_t)u * DD);
    float acc[3] = {0.f, 0.f, 0.f};
    for (int dq = 0; dq < DD / 4; ++dq) {
        float4 v = row[dq];
#pragma unroll
        for (int c = 0; c < 3; ++c) {
            float4 ww = *(const float4*)&sw[c * DD + dq * 4];
            acc[c] += v.x * ww.x + v.y * ww.y + v.z * ww.z + v.w * ww.w;
        }
    }
    float m = fmaxf(acc[0], fmaxf(acc[1], acc[2]));
    float s = 0.f;
#pragma unroll
    for (int c = 0; c < 3; ++c) { acc[c] = __expf(acc[c] - m); s += acc[c]; }
    float inv = 1.f / s;
#pragma unroll
    for (int c = 0; c < 3; ++c) att[u * 3 + c] = acc[c] * inv;
}

// ---------------- K5: fused disen GEMM, 2-phase reg-staged pipeline --------
#define BM 64
#define BK 32
#define SPLITK 16
#define KCH (N_ITEM / SPLITK)                 // 512
#define PLANE ((long long)N_USR * N_ITEM)

__global__ __launch_bounds__(256) void k_disen_gemm(const float* __restrict__ icm,
                                                    const unsigned short* __restrict__ Bt,
                                                    const float* __restrict__ uatt,
                                                    float* __restrict__ part) {
    __shared__ unsigned short sA[BM][40];
    __shared__ unsigned short sB[DD][40];

    const int t  = threadIdx.x;
    const int m0 = blockIdx.x * BM;
    const long long k0b = (long long)blockIdx.y * KCH;

    const int ua = t >> 3;
    const int qa = t & 7;
    const float a00 = uatt[(m0 + ua) * 3 + 0];
    const float a01 = uatt[(m0 + ua) * 3 + 1];
    const float a02 = uatt[(m0 + ua) * 3 + 2];
    const float a10 = uatt[(m0 + ua + 32) * 3 + 0];
    const float a11 = uatt[(m0 + ua + 32) * 3 + 1];
    const float a12 = uatt[(m0 + ua + 32) * 3 + 2];

    const int db = t >> 2;
    const int qb = t & 3;

    const int lane = t & 63;
    const int wv = t >> 6;
    const int wm = wv >> 1, wn = wv & 1;
    const int la = lane & 15, lb = lane >> 4;

    f32x4 acc[2][4];
#pragma unroll
    for (int mi = 0; mi < 2; ++mi)
#pragma unroll
        for (int ni = 0; ni < 4; ++ni) {
            f32x4 z = {0.f, 0.f, 0.f, 0.f};
            acc[mi][ni] = z;
        }

    // reg staging buffers
    float4 rA0[3], rA1[3];
    short8 rB0, rB1;

    // prologue: issue loads for step 0
    {
        const long long base0 = (long long)(m0 + ua) * N_ITEM + k0b + qa * 4;
        rA0[0] = *(const float4*)(icm + base0);
        rA0[1] = *(const float4*)(icm + base0 + PLANE);
        rA0[2] = *(const float4*)(icm + base0 + 2 * PLANE);
        const long long base1 = base0 + 32ll * N_ITEM;
        rA1[0] = *(const float4*)(icm + base1);
        rA1[1] = *(const float4*)(icm + base1 + PLANE);
        rA1[2] = *(const float4*)(icm + base1 + 2 * PLANE);
        const unsigned short* g0 = Bt + (long long)db * N_ITEM + k0b + qb * 8;
        rB0 = *(const short8*)g0;
        rB1 = *(const short8*)(g0 + 64ll * N_ITEM);
    }

    for (int kk = 0; kk < KCH; kk += BK) {
        __syncthreads();   // previous iteration's ds_reads complete
        // convert + store staged regs to LDS
        {
            ushort4 p;
            p.x = f2bf(a00 * rA0[0].x + a01 * rA0[1].x + a02 * rA0[2].x);
            p.y = f2bf(a00 * rA0[0].y + a01 * rA0[1].y + a02 * rA0[2].y);
            p.z = f2bf(a00 * rA0[0].z + a01 * rA0[1].z + a02 * rA0[2].z);
            p.w = f2bf(a00 * rA0[0].w + a01 * rA0[1].w + a02 * rA0[2].w);
            *(ushort4*)(&sA[ua][0] + qa * 4) = p;
            p.x = f2bf(a10 * rA1[0].x + a11 * rA1[1].x + a12 * rA1[2].x);
            p.y = f2bf(a10 * rA1[0].y + a11 * rA1[1].y + a12 * rA1[2].y);
            p.z = f2bf(a10 * rA1[0].z + a11 * rA1[1].z + a12 * rA1[2].z);
            p.w = f2bf(a10 * rA1[0].w + a11 * rA1[1].w + a12 * rA1[2].w);
            *(ushort4*)(&sA[ua + 32][0] + qa * 4) = p;
            *(short8*)(&sB[db][0] + qb * 8) = rB0;
            *(short8*)(&sB[db + 64][0] + qb * 8) = rB1;
        }
        __syncthreads();

        // issue next step's global loads (overlap with ds_read + MFMA)
        if (kk + BK < KCH) {
            const long long k0 = k0b + kk + BK;
            const long long base0 = (long long)(m0 + ua) * N_ITEM + k0 + qa * 4;
            rA0[0] = *(const float4*)(icm + base0);
            rA0[1] = *(const float4*)(icm + base0 + PLANE);
            rA0[2] = *(const float4*)(icm + base0 + 2 * PLANE);
            const long long base1 = base0 + 32ll * N_ITEM;
            rA1[0] = *(const float4*)(icm + base1);
            rA1[1] = *(const float4*)(icm + base1 + PLANE);
            rA1[2] = *(const float4*)(icm + base1 + 2 * PLANE);
            const unsigned short* g0 = Bt + (long long)db * N_ITEM + k0 + qb * 8;
            rB0 = *(const short8*)g0;
            rB1 = *(const short8*)(g0 + 64ll * N_ITEM);
        }

        short8 af[2], bfr[4];
#pragma unroll
        for (int mi = 0; mi < 2; ++mi)
            af[mi] = *(const short8*)(&sA[wm * 32 + mi * 16 + la][0] + lb * 8);
#pragma unroll
        for (int ni = 0; ni < 4; ++ni)
            bfr[ni] = *(const short8*)(&sB[wn * 64 + ni * 16 + la][0] + lb * 8);
#pragma unroll
        for (int mi = 0; mi < 2; ++mi)
#pragma unroll
            for (int ni = 0; ni < 4; ++ni)
                acc[mi][ni] = __builtin_amdgcn_mfma_f32_16x16x32_bf16(
                    af[mi], bfr[ni], acc[mi][ni], 0, 0, 0);
    }

    float* pbase = part + (size_t)blockIdx.y * ((size_t)N_USR * DD);
#pragma unroll
    for (int mi = 0; mi < 2; ++mi)
#pragma unroll
        for (int ni = 0; ni < 4; ++ni)
#pragma unroll
            for (int r = 0; r < 4; ++r) {
                int row = m0 + wm * 32 + mi * 16 + lb * 4 + r;
                int col = wn * 64 + ni * 16 + la;
                pbase[(size_t)row * DD + col] = acc[mi][ni][r];
            }
}

__global__ __launch_bounds__(256) void k_finalize(const float* __restrict__ part,
                                                  float* __restrict__ uout) {
    int i = blockIdx.x * 256 + threadIdx.x;
    float s = uout[i];
#pragma unroll
    for (int k = 0; k < SPLITK; ++k) s += part[(size_t)k * N_USR * DD + i];
    uout[i] = s;
}

// ---------------------------------------------------------------------------
static constexpr size_t algn(size_t x) { return (x + 255) & ~(size_t)255; }

extern "C" void kernel_launch(void* const* d_in, const int* in_sizes, int n_in,
                              void* d_out, int out_size, void* d_ws, size_t ws_size,
                              hipStream_t stream) {
    const float* ent  = (const float*)d_in[0];
    const float* item = (const float*)d_in[1];
    const float* usr  = (const float*)d_in[2];
    const float* rel  = (const float*)d_in[4];
    const int*   eidx = (const int*)d_in[5];
    const int*   etyp = (const int*)d_in[6];
    const float* eimp = (const float*)d_in[7];
    const int*   irow = (const int*)d_in[8];
    const int*   icol = (const int*)d_in[9];
    const float* ival = (const float*)d_in[10];
    const float* uclw = (const float*)d_in[13];
    const float* icm  = (const float*)d_in[14];

    float* out_ent = (float*)d_out;
    float* out_usr = out_ent + (size_t)N_ENT * DD;

    char* w = (char*)d_ws;
    size_t o = 0;
    float* ws_att  = (float*)(w + o);  o = algn(o + (size_t)N_ENT * N_REL * 4);
    float* ws_uatt = (float*)(w + o);  o = algn(o + (size_t)N_USR * N_CLS * 4);
    unsigned short* ws_Bt = (unsigned short*)(w + o); o = algn(o + (size_t)DD * N_ITEM * 2);
    int* deg_e  = (int*)(w + o); o = algn(o + (size_t)N_ENT * 4);
    int* rowp_e = (int*)(w + o); o = algn(o + (size_t)(N_ENT + 1) * 4);
    int* cur_e  = (int*)(w + o); o = algn(o + (size_t)(N_ENT + 1) * 4);
    int* excl_e = (int*)(w + o); o = algn(o + (size_t)N_ENT * 4);
    int* bsum_e = (int*)(w + o); o = algn(o + 1024 * 4);
    int* deg_u  = (int*)(w + o); o = algn(o + (size_t)N_USR * 4);
    int* rowp_u = (int*)(w + o); o = algn(o + (size_t)(N_USR + 1) * 4);
    int* cur_u  = (int*)(w + o); o = algn(o + (size_t)(N_USR + 1) * 4);
    int* excl_u = (int*)(w + o); o = algn(o + (size_t)N_USR * 4);
    int* bsum_u = (int*)(w + o); o = algn(o + 1024 * 4);
    int2* pack_e = (int2*)(w + o); o = algn(o + (size_t)N_EDGES * 8);
    int2* pack_u = (int2*)(w + o); o = algn(o + (size_t)NNZ * 8);
    float* part  = (float*)(w + o); o = algn(o + (size_t)SPLITK * N_USR * DD * 4);

    (void)in_sizes; (void)n_in; (void)ws_size; (void)out_size;

    const int nb_e = (N_ENT + 1023) / 1024;   // 98
    const int nb_u = (N_USR + 1023) / 1024;   // 4

    hipMemsetAsync(deg_e, 0, (size_t)N_ENT * 4, stream);
    hipMemsetAsync(deg_u, 0, (size_t)N_USR * 4, stream);
    k_hist_all<<<(N_EDGES + 255) / 256, 256, 0, stream>>>(eidx, irow, deg_e, deg_u);
    k_scan_local<<<nb_e, 1024, 0, stream>>>(deg_e, N_ENT, excl_e, bsum_e);
    k_scan_local<<<nb_u, 1024, 0, stream>>>(deg_u, N_USR, excl_u, bsum_u);
    k_scan_bsum<<<1, 1024, 0, stream>>>(bsum_e, nb_e);
    k_scan_bsum<<<1, 1024, 0, stream>>>(bsum_u, nb_u);
    k_scan_add<<<nb_e, 1024, 0, stream>>>(excl_e, bsum_e, N_ENT, N_EDGES, rowp_e, cur_e);
    k_scan_add<<<nb_u, 1024, 0, stream>>>(excl_u, bsum_u, N_USR, NNZ, rowp_u, cur_u);

    k_ent_att<<<(N_ENT + 255) / 256, 256, 0, stream>>>(ent, rel, ws_att);
    k_item2_t<<<dim3(N_ITEM / 32, DD / 32), 256, 0, stream>>>(item, rel, ws_Bt);
    k_user_att<<<N_USR / 256, 256, 0, stream>>>(usr, uclw, ws_uatt);

    k_scatter_pack_e<<<(N_EDGES + 255) / 256, 256, 0, stream>>>(eidx, etyp, eimp, ws_att,
                                                                cur_e, pack_e);
    k_scatter_pack_u<<<(NNZ + 255) / 256, 256, 0, stream>>>(irow, icol, ival, cur_u, pack_u);

    k_edge_agg2<<<N_ENT / 4, 256, 0, stream>>>(ent, rel, pack_e, rowp_e, out_ent);
    k_user_gather2<<<N_USR / 4, 256, 0, stream>>>(ent, pack_u, rowp_u, out_usr);
    k_disen_gemm<<<dim3(N_USR / BM, SPLITK), 256, 0, stream>>>(icm, ws_Bt, ws_uatt, part);
    k_finalize<<<(N_USR * DD) / 256, 256, 0, stream>>>(part, out_usr);
}

// Round 5
// 401.478 us; speedup vs baseline: 2.4629x; 1.0045x over previous
//
#include <hip/hip_runtime.h>

#define N_ENT   100000
#define N_USR   4096
#define N_ITEM  8192
#define N_REL   32
#define N_CLS   3
#define DD      128
#define N_EDGES 800000
#define NNZ     204800

typedef __attribute__((ext_vector_type(8))) short short8;
typedef __attribute__((ext_vector_type(4))) float f32x4;

static __device__ __forceinline__ unsigned short f2bf(float x) {
    unsigned int u = __builtin_bit_cast(unsigned int, x);
    u = (u + 0x7fffu + ((u >> 16) & 1u)) >> 16;
    return (unsigned short)u;
}
static __device__ __forceinline__ float bflo(unsigned int v) {
    return __uint_as_float(v << 16);
}
static __device__ __forceinline__ float bfhi(unsigned int v) {
    return __uint_as_float(v & 0xffff0000u);
}

// ---------------- CSR build ------------------------------------------------
__global__ __launch_bounds__(256) void k_hist_all(const int* __restrict__ ekeys,
                                                  const int* __restrict__ ukeys,
                                                  int* __restrict__ deg_e,
                                                  int* __restrict__ deg_u) {
    int i = blockIdx.x * 256 + threadIdx.x;
    if (i < N_EDGES) atomicAdd(&deg_e[ekeys[i]], 1);
    if (i < NNZ) atomicAdd(&deg_u[ukeys[i]], 1);
}

#define NB_E ((N_ENT + 1023) / 1024)   // 98
#define NB_U ((N_USR + 1023) / 1024)   // 4

__global__ __launch_bounds__(1024) void k_scan_local_all(const int* __restrict__ deg_e,
                                                         const int* __restrict__ deg_u,
                                                         int* __restrict__ excl_e,
                                                         int* __restrict__ excl_u,
                                                         int* __restrict__ bsum_e,
                                                         int* __restrict__ bsum_u) {
    __shared__ int lds[1024];
    const int t = threadIdx.x;
    const int* deg; int* excl; int* bsum; int n, b;
    if (blockIdx.x < NB_E) { deg = deg_e; excl = excl_e; bsum = bsum_e; n = N_ENT; b = blockIdx.x; }
    else                   { deg = deg_u; excl = excl_u; bsum = bsum_u; n = N_USR; b = blockIdx.x - NB_E; }
    int i = b * 1024 + t;
    int v = (i < n) ? deg[i] : 0;
    lds[t] = v;
    __syncthreads();
    for (int off = 1; off < 1024; off <<= 1) {
        int a = (t >= off) ? lds[t - off] : 0;
        __syncthreads();
        lds[t] += a;
        __syncthreads();
    }
    if (i < n) excl[i] = lds[t] - v;
    if (t == 1023) bsum[b] = lds[1023];
}

__global__ __launch_bounds__(1024) void k_scan_bsum_all(int* __restrict__ bsum_e,
                                                        int* __restrict__ bsum_u) {
    __shared__ int lds[1024];
    int* bsum = (blockIdx.x == 0) ? bsum_e : bsum_u;
    int nb = (blockIdx.x == 0) ? NB_E : NB_U;
    int t = threadIdx.x;
    int v = (t < nb) ? bsum[t] : 0;
    lds[t] = v;
    __syncthreads();
    for (int off = 1; off < 1024; off <<= 1) {
        int a = (t >= off) ? lds[t - off] : 0;
        __syncthreads();
        lds[t] += a;
        __syncthreads();
    }
    if (t < nb) bsum[t] = lds[t] - v;
}

__global__ __launch_bounds__(1024) void k_scan_add_all(const int* __restrict__ excl_e,
                                                       const int* __restrict__ excl_u,
                                                       const int* __restrict__ bsum_e,
                                                       const int* __restrict__ bsum_u,
                                                       int* __restrict__ rowp_e,
                                                       int* __restrict__ rowp_u,
                                                       int* __restrict__ cur_e,
                                                       int* __restrict__ cur_u) {
    const int t = threadIdx.x;
    const int* excl; const int* bsum; int* rowp; int* cur; int n, ntot, b;
    if (blockIdx.x < NB_E) { excl = excl_e; bsum = bsum_e; rowp = rowp_e; cur = cur_e; n = N_ENT; ntot = N_EDGES; b = blockIdx.x; }
    else                   { excl = excl_u; bsum = bsum_u; rowp = rowp_u; cur = cur_u; n = N_USR; ntot = NNZ; b = blockIdx.x - NB_E; }
    int i = b * 1024 + t;
    if (i < n) {
        int v = excl[i] + bsum[b];
        rowp[i] = v;
        cur[i] = v;
    }
    if (i == 0) rowp[n] = ntot;
}

// ---------------- K1: ent_rel_att softmax + bf16 entity table --------------
__global__ __launch_bounds__(256) void k_ent_att(const float* __restrict__ ent,
                                                 const float* __restrict__ rel,
                                                 float* __restrict__ att,
                                                 unsigned short* __restrict__ entbf) {
    __shared__ float srel[N_REL * DD];
    for (int i = threadIdx.x; i < N_REL * DD; i += 256) srel[i] = rel[i];
    __syncthreads();
    int e = blockIdx.x * 256 + threadIdx.x;
    if (e >= N_ENT) return;
    const float4* row = (const float4*)(ent + (size_t)e * DD);
    unsigned short* brow = entbf + (size_t)e * DD;
    float acc[N_REL];
#pragma unroll
    for (int r = 0; r < N_REL; ++r) acc[r] = 0.f;
    for (int dq = 0; dq < DD / 4; ++dq) {
        float4 v = row[dq];
        ushort4 bv;
        bv.x = f2bf(v.x); bv.y = f2bf(v.y); bv.z = f2bf(v.z); bv.w = f2bf(v.w);
        *(ushort4*)(brow + dq * 4) = bv;
#pragma unroll
        for (int r = 0; r < N_REL; ++r) {
            float4 w = *(const float4*)&srel[r * DD + dq * 4];
            acc[r] += v.x * w.x + v.y * w.y + v.z * w.z + v.w * w.w;
        }
    }
    float m = acc[0];
#pragma unroll
    for (int r = 1; r < N_REL; ++r) m = fmaxf(m, acc[r]);
    float s = 0.f;
#pragma unroll
    for (int r = 0; r < N_REL; ++r) { acc[r] = __expf(acc[r] - m); s += acc[r]; }
    float inv = 1.f / s;
    float* o = att + (size_t)e * N_REL;
#pragma unroll
    for (int r = 0; r < N_REL; ++r) o[r] = acc[r] * inv;
}

// ---------------- fused scatter+pack (edges and users in one kernel) -------
__global__ __launch_bounds__(256) void k_scatter_pack_all(const int* __restrict__ eidx,
                                                          const int* __restrict__ etyp,
                                                          const float* __restrict__ eimp,
                                                          const float* __restrict__ att,
                                                          const int* __restrict__ irow,
                                                          const int* __restrict__ icol,
                                                          const float* __restrict__ ival,
                                                          int* __restrict__ cur_e,
                                                          int* __restrict__ cur_u,
                                                          int2* __restrict__ pack_e,
                                                          int2* __restrict__ pack_u) {
    int i = blockIdx.x * 256 + threadIdx.x;
    if (i < N_EDGES) {
        int h = eidx[i], tl = eidx[N_EDGES + i], r = etyp[i];
        float s = att[(size_t)h * N_REL + r] * eimp[i];
        int p = atomicAdd(&cur_e[h], 1);
        int2 pk;
        pk.x = tl | (r << 24);
        pk.y = __float_as_int(s);
        pack_e[p] = pk;
    }
    if (i < NNZ) {
        int p = atomicAdd(&cur_u[irow[i]], 1);
        int2 pk;
        pk.x = icol[i];
        pk.y = __float_as_int(ival[i]);
        pack_u[p] = pk;
    }
}

// ---------------- K2: edge aggregation, bf16 gather, 8-deep ----------------
__global__ __launch_bounds__(256) void k_edge_agg2(const unsigned short* __restrict__ entbf,
                                                   const float* __restrict__ rel,
                                                   const int2* __restrict__ pack,
                                                   const int* __restrict__ rowp,
                                                   float* __restrict__ out) {
    __shared__ float srel[N_REL * DD];
    for (int i = threadIdx.x; i < N_REL * DD; i += 256) srel[i] = rel[i];
    __syncthreads();
    const int lane = threadIdx.x & 63;
    const int h = blockIdx.x * 4 + (threadIdx.x >> 6);   // 25000*4 == 100000
    const int beg = rowp[h], end = rowp[h + 1];
    float ax = 0.f, ay = 0.f;
    if (beg < end) {
        for (int j = beg; j < end; j += 8) {
            int2 pk[8];
#pragma unroll
            for (int k = 0; k < 8; ++k) pk[k] = pack[min(j + k, end - 1)];
            unsigned int bv[8];
            float sc[8];
#pragma unroll
            for (int k = 0; k < 8; ++k) {
                sc[k] = (j + k < end) ? __int_as_float(pk[k].y) : 0.f;
                bv[k] = ((const unsigned int*)(entbf + (size_t)(pk[k].x & 0xFFFFFF) * DD))[lane];
            }
#pragma unroll
            for (int k = 0; k < 8; ++k) {
                float2 a = ((const float2*)(srel + (size_t)(((unsigned)pk[k].x) >> 24) * DD))[lane];
                ax = fmaf(a.x * bflo(bv[k]), sc[k], ax);
                ay = fmaf(a.y * bfhi(bv[k]), sc[k], ay);
            }
        }
    }
    float2 o; o.x = ax; o.y = ay;
    ((float2*)(out + (size_t)h * DD))[lane] = o;
}

// ---------------- K4b+K4c merged: item2 transpose + user_cls_att -----------
__global__ __launch_bounds__(256) void k_item2_uatt(const float* __restrict__ item,
                                                    const float* __restrict__ rel,
                                                    unsigned short* __restrict__ Bt,
                                                    const float* __restrict__ usr,
                                                    const float* __restrict__ w,
                                                    float* __restrict__ att) {
    if (blockIdx.x < 1024) {
        __shared__ float tile[32][33];
        __shared__ float ssum[32];
        const int bx = blockIdx.x & 255, by = blockIdx.x >> 8;
        const int tx = threadIdx.x & 31, ty = threadIdx.x >> 5;
        const int i0 = bx * 32, d0 = by * 32;
        if (threadIdx.x < 32) {
            float s = 0.f;
            for (int r = 0; r < N_REL; ++r) s += rel[r * DD + d0 + threadIdx.x];
            ssum[threadIdx.x] = s;
        }
#pragma unroll
        for (int rr = 0; rr < 4; ++rr)
            tile[ty + 8 * rr][tx] = item[(size_t)(i0 + ty + 8 * rr) * DD + d0 + tx];
        __syncthreads();
#pragma unroll
        for (int rr = 0; rr < 4; ++rr) {
            int d = d0 + ty + 8 * rr;
            Bt[(size_t)d * N_ITEM + i0 + tx] = f2bf(tile[tx][ty + 8 * rr] * ssum[ty + 8 * rr]);
        }
    } else {
        __shared__ float sw[N_CLS * DD];
        for (int i = threadIdx.x; i < N_CLS * DD; i += 256) sw[i] = w[i];
        __syncthreads();
        int u = (blockIdx.x - 1024) * 256 + threadIdx.x;
        const float4* row = (const float4*)(usr + (size_t)u * DD);
        float acc[3] = {0.f, 0.f, 0.f};
        for (int dq = 0; dq < DD / 4; ++dq) {
            float4 v = row[dq];
#pragma unroll
            for (int c = 0; c < 3; ++c) {
                float4 ww = *(const float4*)&sw[c * DD + dq * 4];
                acc[c] += v.x * ww.x + v.y * ww.y + v.z * ww.z + v.w * ww.w;
            }
        }
        float m = fmaxf(acc[0], fmaxf(acc[1], acc[2]));
        float s = 0.f;
#pragma unroll
        for (int c = 0; c < 3; ++c) { acc[c] = __expf(acc[c] - m); s += acc[c]; }
        float inv = 1.f / s;
#pragma unroll
        for (int c = 0; c < 3; ++c) att[u * 3 + c] = acc[c] * inv;
    }
}

// ---------------- K5: fused disen GEMM, 2-phase reg-staged pipeline --------
#define BM 64
#define BK 32
#define SPLITK 16
#define KCH (N_ITEM / SPLITK)                 // 512
#define PLANE ((long long)N_USR * N_ITEM)

__global__ __launch_bounds__(256) void k_disen_gemm(const float* __restrict__ icm,
                                                    const unsigned short* __restrict__ Bt,
                                                    const float* __restrict__ uatt,
                                                    float* __restrict__ part) {
    __shared__ unsigned short sA[BM][40];
    __shared__ unsigned short sB[DD][40];

    const int t  = threadIdx.x;
    const int m0 = blockIdx.x * BM;
    const long long k0b = (long long)blockIdx.y * KCH;

    const int ua = t >> 3;
    const int qa = t & 7;
    const float a00 = uatt[(m0 + ua) * 3 + 0];
    const float a01 = uatt[(m0 + ua) * 3 + 1];
    const float a02 = uatt[(m0 + ua) * 3 + 2];
    const float a10 = uatt[(m0 + ua + 32) * 3 + 0];
    const float a11 = uatt[(m0 + ua + 32) * 3 + 1];
    const float a12 = uatt[(m0 + ua + 32) * 3 + 2];

    const int db = t >> 2;
    const int qb = t & 3;

    const int lane = t & 63;
    const int wv = t >> 6;
    const int wm = wv >> 1, wn = wv & 1;
    const int la = lane & 15, lb = lane >> 4;

    f32x4 acc[2][4];
#pragma unroll
    for (int mi = 0; mi < 2; ++mi)
#pragma unroll
        for (int ni = 0; ni < 4; ++ni) {
            f32x4 z = {0.f, 0.f, 0.f, 0.f};
            acc[mi][ni] = z;
        }

    float4 rA0[3], rA1[3];
    short8 rB0, rB1;

    {
        const long long base0 = (long long)(m0 + ua) * N_ITEM + k0b + qa * 4;
        rA0[0] = *(const float4*)(icm + base0);
        rA0[1] = *(const float4*)(icm + base0 + PLANE);
        rA0[2] = *(const float4*)(icm + base0 + 2 * PLANE);
        const long long base1 = base0 + 32ll * N_ITEM;
        rA1[0] = *(const float4*)(icm + base1);
        rA1[1] = *(const float4*)(icm + base1 + PLANE);
        rA1[2] = *(const float4*)(icm + base1 + 2 * PLANE);
        const unsigned short* g0 = Bt + (long long)db * N_ITEM + k0b + qb * 8;
        rB0 = *(const short8*)g0;
        rB1 = *(const short8*)(g0 + 64ll * N_ITEM);
    }

    for (int kk = 0; kk < KCH; kk += BK) {
        __syncthreads();
        {
            ushort4 p;
            p.x = f2bf(a00 * rA0[0].x + a01 * rA0[1].x + a02 * rA0[2].x);
            p.y = f2bf(a00 * rA0[0].y + a01 * rA0[1].y + a02 * rA0[2].y);
            p.z = f2bf(a00 * rA0[0].z + a01 * rA0[1].z + a02 * rA0[2].z);
            p.w = f2bf(a00 * rA0[0].w + a01 * rA0[1].w + a02 * rA0[2].w);
            *(ushort4*)(&sA[ua][0] + qa * 4) = p;
            p.x = f2bf(a10 * rA1[0].x + a11 * rA1[1].x + a12 * rA1[2].x);
            p.y = f2bf(a10 * rA1[0].y + a11 * rA1[1].y + a12 * rA1[2].y);
            p.z = f2bf(a10 * rA1[0].z + a11 * rA1[1].z + a12 * rA1[2].z);
            p.w = f2bf(a10 * rA1[0].w + a11 * rA1[1].w + a12 * rA1[2].w);
            *(ushort4*)(&sA[ua + 32][0] + qa * 4) = p;
            *(short8*)(&sB[db][0] + qb * 8) = rB0;
            *(short8*)(&sB[db + 64][0] + qb * 8) = rB1;
        }
        __syncthreads();

        if (kk + BK < KCH) {
            const long long k0 = k0b + kk + BK;
            const long long base0 = (long long)(m0 + ua) * N_ITEM + k0 + qa * 4;
            rA0[0] = *(const float4*)(icm + base0);
            rA0[1] = *(const float4*)(icm + base0 + PLANE);
            rA0[2] = *(const float4*)(icm + base0 + 2 * PLANE);
            const long long base1 = base0 + 32ll * N_ITEM;
            rA1[0] = *(const float4*)(icm + base1);
            rA1[1] = *(const float4*)(icm + base1 + PLANE);
            rA1[2] = *(const float4*)(icm + base1 + 2 * PLANE);
            const unsigned short* g0 = Bt + (long long)db * N_ITEM + k0 + qb * 8;
            rB0 = *(const short8*)g0;
            rB1 = *(const short8*)(g0 + 64ll * N_ITEM);
        }

        short8 af[2], bfr[4];
#pragma unroll
        for (int mi = 0; mi < 2; ++mi)
            af[mi] = *(const short8*)(&sA[wm * 32 + mi * 16 + la][0] + lb * 8);
#pragma unroll
        for (int ni = 0; ni < 4; ++ni)
            bfr[ni] = *(const short8*)(&sB[wn * 64 + ni * 16 + la][0] + lb * 8);
#pragma unroll
        for (int mi = 0; mi < 2; ++mi)
#pragma unroll
            for (int ni = 0; ni < 4; ++ni)
                acc[mi][ni] = __builtin_amdgcn_mfma_f32_16x16x32_bf16(
                    af[mi], bfr[ni], acc[mi][ni], 0, 0, 0);
    }

    float* pbase = part + (size_t)blockIdx.y * ((size_t)N_USR * DD);
#pragma unroll
    for (int mi = 0; mi < 2; ++mi)
#pragma unroll
        for (int ni = 0; ni < 4; ++ni)
#pragma unroll
            for (int r = 0; r < 4; ++r) {
                int row = m0 + wm * 32 + mi * 16 + lb * 4 + r;
                int col = wn * 64 + ni * 16 + la;
                pbase[(size_t)row * DD + col] = acc[mi][ni][r];
            }
}

// ---------------- K6: fused user gather + split-K reduce -------------------
__global__ __launch_bounds__(256) void k_user_final(const unsigned short* __restrict__ entbf,
                                                    const int2* __restrict__ pack,
                                                    const int* __restrict__ rowp,
                                                    const float* __restrict__ part,
                                                    float* __restrict__ uout) {
    const int lane = threadIdx.x & 63;
    const int u = blockIdx.x * 4 + (threadIdx.x >> 6);   // 1024*4 == 4096
    const int beg = rowp[u], end = rowp[u + 1];
    float ax = 0.f, ay = 0.f;
    if (beg < end) {
        for (int j = beg; j < end; j += 8) {
            int2 pk[8];
#pragma unroll
            for (int k = 0; k < 8; ++k) pk[k] = pack[min(j + k, end - 1)];
            unsigned int bv[8];
            float sc[8];
#pragma unroll
            for (int k = 0; k < 8; ++k) {
                sc[k] = (j + k < end) ? __int_as_float(pk[k].y) : 0.f;
                bv[k] = ((const unsigned int*)(entbf + (size_t)pk[k].x * DD))[lane];
            }
#pragma unroll
            for (int k = 0; k < 8; ++k) {
                ax = fmaf(bflo(bv[k]), sc[k], ax);
                ay = fmaf(bfhi(bv[k]), sc[k], ay);
            }
        }
    }
#pragma unroll
    for (int k = 0; k < SPLITK; ++k) {
        float2 p = ((const float2*)(part + (size_t)k * N_USR * DD + (size_t)u * DD))[lane];
        ax += p.x;
        ay += p.y;
    }
    float2 o; o.x = ax; o.y = ay;
    ((float2*)(uout + (size_t)u * DD))[lane] = o;
}

// ---------------------------------------------------------------------------
static constexpr size_t algn(size_t x) { return (x + 255) & ~(size_t)255; }

extern "C" void kernel_launch(void* const* d_in, const int* in_sizes, int n_in,
                              void* d_out, int out_size, void* d_ws, size_t ws_size,
                              hipStream_t stream) {
    const float* ent  = (const float*)d_in[0];
    const float* item = (const float*)d_in[1];
    const float* usr  = (const float*)d_in[2];
    const float* rel  = (const float*)d_in[4];
    const int*   eidx = (const int*)d_in[5];
    const int*   etyp = (const int*)d_in[6];
    const float* eimp = (const float*)d_in[7];
    const int*   irow = (const int*)d_in[8];
    const int*   icol = (const int*)d_in[9];
    const float* ival = (const float*)d_in[10];
    const float* uclw = (const float*)d_in[13];
    const float* icm  = (const float*)d_in[14];

    float* out_ent = (float*)d_out;
    float* out_usr = out_ent + (size_t)N_ENT * DD;

    char* w = (char*)d_ws;
    size_t o = 0;
    float* ws_att  = (float*)(w + o);  o = algn(o + (size_t)N_ENT * N_REL * 4);
    float* ws_uatt = (float*)(w + o);  o = algn(o + (size_t)N_USR * N_CLS * 4);
    unsigned short* ws_Bt = (unsigned short*)(w + o); o = algn(o + (size_t)DD * N_ITEM * 2);
    unsigned short* ws_entbf = (unsigned short*)(w + o); o = algn(o + (size_t)N_ENT * DD * 2);
    // deg_e and deg_u contiguous -> single memset
    int* deg_e  = (int*)(w + o); o += (size_t)N_ENT * 4;
    int* deg_u  = (int*)(w + o); o = algn(o + (size_t)N_USR * 4);
    int* rowp_e = (int*)(w + o); o = algn(o + (size_t)(N_ENT + 1) * 4);
    int* cur_e  = (int*)(w + o); o = algn(o + (size_t)(N_ENT + 1) * 4);
    int* excl_e = (int*)(w + o); o = algn(o + (size_t)N_ENT * 4);
    int* bsum_e = (int*)(w + o); o = algn(o + 1024 * 4);
    int* rowp_u = (int*)(w + o); o = algn(o + (size_t)(N_USR + 1) * 4);
    int* cur_u  = (int*)(w + o); o = algn(o + (size_t)(N_USR + 1) * 4);
    int* excl_u = (int*)(w + o); o = algn(o + (size_t)N_USR * 4);
    int* bsum_u = (int*)(w + o); o = algn(o + 1024 * 4);
    int2* pack_e = (int2*)(w + o); o = algn(o + (size_t)N_EDGES * 8);
    int2* pack_u = (int2*)(w + o); o = algn(o + (size_t)NNZ * 8);
    float* part  = (float*)(w + o); o = algn(o + (size_t)SPLITK * N_USR * DD * 4);

    (void)in_sizes; (void)n_in; (void)ws_size; (void)out_size;

    hipMemsetAsync(deg_e, 0, (size_t)(N_ENT + N_USR) * 4, stream);
    k_hist_all<<<(N_EDGES + 255) / 256, 256, 0, stream>>>(eidx, irow, deg_e, deg_u);
    k_scan_local_all<<<NB_E + NB_U, 1024, 0, stream>>>(deg_e, deg_u, excl_e, excl_u,
                                                       bsum_e, bsum_u);
    k_scan_bsum_all<<<2, 1024, 0, stream>>>(bsum_e, bsum_u);
    k_scan_add_all<<<NB_E + NB_U, 1024, 0, stream>>>(excl_e, excl_u, bsum_e, bsum_u,
                                                     rowp_e, rowp_u, cur_e, cur_u);

    k_ent_att<<<(N_ENT + 255) / 256, 256, 0, stream>>>(ent, rel, ws_att, ws_entbf);
    k_item2_uatt<<<1024 + 16, 256, 0, stream>>>(item, rel, ws_Bt, usr, uclw, ws_uatt);

    k_scatter_pack_all<<<(N_EDGES + 255) / 256, 256, 0, stream>>>(
        eidx, etyp, eimp, ws_att, irow, icol, ival, cur_e, cur_u, pack_e, pack_u);

    k_edge_agg2<<<N_ENT / 4, 256, 0, stream>>>(ws_entbf, rel, pack_e, rowp_e, out_ent);
    k_disen_gemm<<<dim3(N_USR / BM, SPLITK), 256, 0, stream>>>(icm, ws_Bt, ws_uatt, part);
    k_user_final<<<N_USR / 4, 256, 0, stream>>>(ws_entbf, pack_u, rowp_u, part, out_usr);
}